// Round 1
// baseline (2846.518 us; speedup 1.0000x reference)
//
#include <hip/hip_runtime.h>
#include <math.h>

#define N_NODES 50000
#define E_EDGES 1600000
#define F_IN_DIM 256
#define H_HEADS 4
#define C_CH 32
#define HC 128
#define NUM_CLASSES 16
#define NUM_GRAPHS 64
#define ETOT (E_EDGES + N_NODES)
#define NEG_SLOPE 0.2f

// ---- monotonic float<->uint mapping for atomicMax on floats ----
__device__ __forceinline__ unsigned fmap(float f) {
    unsigned u = __float_as_uint(f);
    return (u & 0x80000000u) ? ~u : (u | 0x80000000u);
}
__device__ __forceinline__ float funmap(unsigned u) {
    return (u & 0x80000000u) ? __uint_as_float(u ^ 0x80000000u)
                             : __uint_as_float(~u);
}

// ---- GEMM: Hout[n, 0:128] = X[n, 0:K] @ W[K, 128] ----
// one block = 32 rows, 128 threads (one per output column). X tile in LDS.
template <int K>
__global__ __launch_bounds__(128) void gemm_tile(const float* __restrict__ X,
                                                 const float* __restrict__ W,
                                                 float* __restrict__ Hout) {
    __shared__ float xs[32 * K];
    const int n0 = blockIdx.x * 32;
    const int t = threadIdx.x;  // 0..127 output column
    for (int i = t; i < 32 * K; i += 128) {
        int r = i / K;
        int k = i - r * K;
        int n = n0 + r;
        xs[i] = (n < N_NODES) ? X[(size_t)n * K + k] : 0.f;
    }
    __syncthreads();
    float acc[32];
#pragma unroll
    for (int r = 0; r < 32; ++r) acc[r] = 0.f;
    for (int k = 0; k < K; k += 4) {
        float w0 = W[(k + 0) * HC + t];
        float w1 = W[(k + 1) * HC + t];
        float w2 = W[(k + 2) * HC + t];
        float w3 = W[(k + 3) * HC + t];
#pragma unroll
        for (int r = 0; r < 32; ++r) {
            const float4 xv = *reinterpret_cast<const float4*>(&xs[r * K + k]);
            acc[r] = fmaf(xv.x, w0,
                     fmaf(xv.y, w1,
                     fmaf(xv.z, w2,
                     fmaf(xv.w, w3, acc[r]))));
        }
    }
#pragma unroll
    for (int r = 0; r < 32; ++r) {
        int n = n0 + r;
        if (n < N_NODES) Hout[(size_t)n * HC + t] = acc[r];
    }
}

// ---- per-node attention logits: as/ad [N, H] ----
__global__ void alpha_kernel(const float* __restrict__ Hb,
                             const float* __restrict__ a_src,
                             const float* __restrict__ a_dst,
                             float* __restrict__ as, float* __restrict__ ad) {
    int i = blockIdx.x * blockDim.x + threadIdx.x;  // n*H + h
    if (i >= N_NODES * H_HEADS) return;
    int h = i & 3;
    const float* hp = Hb + (size_t)(i >> 2) * HC + h * C_CH;
    float ssum = 0.f, dsum = 0.f;
#pragma unroll
    for (int c = 0; c < C_CH; ++c) {
        float v = hp[c];
        ssum += v * a_src[h * C_CH + c];
        dsum += v * a_dst[h * C_CH + c];
    }
    as[i] = ssum;
    ad[i] = dsum;
}

__global__ void set_minf_kernel(unsigned* __restrict__ m) {
    int i = blockIdx.x * blockDim.x + threadIdx.x;
    if (i < N_NODES * H_HEADS) m[i] = fmap(-INFINITY);
}

// ---- pass 1: segment max of leaky_relu(e) over dst ----
__global__ void edge_max_kernel(const int* __restrict__ ei,
                                const float* __restrict__ as,
                                const float* __restrict__ ad,
                                unsigned* __restrict__ m) {
    int i = blockIdx.x * blockDim.x + threadIdx.x;  // e*H + h
    if (i >= ETOT * H_HEADS) return;
    int e = i >> 2, h = i & 3;
    int s, d;
    if (e < E_EDGES) { s = ei[e]; d = ei[E_EDGES + e]; }
    else             { s = d = e - E_EDGES; }
    float ev = as[s * 4 + h] + ad[d * 4 + h];
    ev = ev > 0.f ? ev : ev * NEG_SLOPE;
    atomicMax(&m[d * 4 + h], fmap(ev));
}

// ---- pass 2: z += p ; out[dst] += p * h[src]  (32 lanes per edge-head) ----
__global__ void edge_accum_kernel(const int* __restrict__ ei,
                                  const float* __restrict__ as,
                                  const float* __restrict__ ad,
                                  const unsigned* __restrict__ m,
                                  const float* __restrict__ Hb,
                                  float* __restrict__ z,
                                  float* __restrict__ out) {
    long long gid = (long long)blockIdx.x * blockDim.x + threadIdx.x;
    long long group = gid >> 5;
    int lane = (int)(gid & 31);
    if (group >= (long long)ETOT * H_HEADS) return;
    int e = (int)(group >> 2);
    int h = (int)(group & 3);
    int s, d;
    if (e < E_EDGES) { s = ei[e]; d = ei[E_EDGES + e]; }
    else             { s = d = e - E_EDGES; }
    float ev = as[s * 4 + h] + ad[d * 4 + h];
    ev = ev > 0.f ? ev : ev * NEG_SLOPE;
    float p = __expf(ev - funmap(m[d * 4 + h]));
    if (lane == 0) atomicAdd(&z[d * 4 + h], p);
    float hv = Hb[(size_t)s * HC + h * C_CH + lane];
    atomicAdd(&out[(size_t)d * HC + h * C_CH + lane], p * hv);
}

// ---- out = relu(out / z + bias) ----
__global__ void finalize_kernel(float* __restrict__ out,
                                const float* __restrict__ z,
                                const float* __restrict__ b) {
    int i = blockIdx.x * blockDim.x + threadIdx.x;
    if (i >= N_NODES * HC) return;
    int c = i & 127;
    int n = i >> 7;
    int h = c >> 5;
    float v = out[i] / z[n * 4 + h] + b[c];
    out[i] = v > 0.f ? v : 0.f;
}

// ---- global mean pool: atomically accumulate sums + counts ----
__global__ void pool_kernel(const float* __restrict__ out,
                            const int* __restrict__ batch,
                            float* __restrict__ sums, float* __restrict__ cnt) {
    int i = blockIdx.x * blockDim.x + threadIdx.x;
    if (i >= N_NODES * HC) return;
    int n = i >> 7, c = i & 127;
    int g = batch[n];
    atomicAdd(&sums[(size_t)g * HC + c], out[i]);
    if (c == 0) atomicAdd(&cnt[g], 1.0f);
}

// ---- classifier: mean -> 128x32 -> 32x16 -> sigmoid ----
__global__ void classifier_kernel(const float* __restrict__ sums,
                                  const float* __restrict__ cnt,
                                  const float* __restrict__ Wc1,
                                  const float* __restrict__ bc1,
                                  const float* __restrict__ Wc2,
                                  const float* __restrict__ bc2,
                                  float* __restrict__ outp) {
    int g = threadIdx.x;
    if (g >= NUM_GRAPHS) return;
    float inv = 1.0f / cnt[g];
    float hidden[C_CH];
#pragma unroll 4
    for (int j = 0; j < C_CH; ++j) {
        float acc = bc1[j];
        for (int c = 0; c < HC; ++c)
            acc += (sums[g * HC + c] * inv) * Wc1[c * C_CH + j];
        hidden[j] = acc;
    }
    for (int k = 0; k < NUM_CLASSES; ++k) {
        float acc = bc2[k];
#pragma unroll
        for (int j = 0; j < C_CH; ++j) acc += hidden[j] * Wc2[j * NUM_CLASSES + k];
        outp[g * NUM_CLASSES + k] = 1.0f / (1.0f + __expf(-acc));
    }
}

extern "C" void kernel_launch(void* const* d_in, const int* in_sizes, int n_in,
                              void* d_out, int out_size, void* d_ws, size_t ws_size,
                              hipStream_t stream) {
    const float* x   = (const float*)d_in[0];
    const int*   ei  = (const int*)  d_in[1];
    const int*   bat = (const int*)  d_in[2];
    const float* W1  = (const float*)d_in[3];
    const float* as1 = (const float*)d_in[4];
    const float* ad1 = (const float*)d_in[5];
    const float* b1  = (const float*)d_in[6];
    const float* W2  = (const float*)d_in[7];
    const float* as2 = (const float*)d_in[8];
    const float* ad2 = (const float*)d_in[9];
    const float* b2  = (const float*)d_in[10];
    const float* Wc1 = (const float*)d_in[11];
    const float* bc1 = (const float*)d_in[12];
    const float* Wc2 = (const float*)d_in[13];
    const float* bc2 = (const float*)d_in[14];
    float* outp = (float*)d_out;

    char* ws = (char*)d_ws;
    float*    hbuf = (float*)ws;  ws += (size_t)N_NODES * HC * 4;
    float*    obuf = (float*)ws;  ws += (size_t)N_NODES * HC * 4;
    float*    asb  = (float*)ws;  ws += (size_t)N_NODES * H_HEADS * 4;
    float*    adb  = (float*)ws;  ws += (size_t)N_NODES * H_HEADS * 4;
    unsigned* mb   = (unsigned*)ws; ws += (size_t)N_NODES * H_HEADS * 4;
    float*    zb   = (float*)ws;  ws += (size_t)N_NODES * H_HEADS * 4;
    float*    sums = (float*)ws;  ws += (size_t)NUM_GRAPHS * HC * 4;
    float*    cnt  = (float*)ws;  ws += (size_t)NUM_GRAPHS * 4;

    const int nh_blocks   = (N_NODES * H_HEADS + 255) / 256;
    const int emax_blocks = (ETOT * H_HEADS + 255) / 256;
    const long long accum_threads = (long long)ETOT * H_HEADS * 32;
    const int eacc_blocks = (int)((accum_threads + 255) / 256);
    const int nhc_blocks  = (N_NODES * HC + 255) / 256;
    const int gemm_blocks = (N_NODES + 31) / 32;

    // ---------------- layer 1 ----------------
    gemm_tile<F_IN_DIM><<<gemm_blocks, 128, 0, stream>>>(x, W1, hbuf);
    alpha_kernel<<<nh_blocks, 256, 0, stream>>>(hbuf, as1, ad1, asb, adb);
    hipMemsetAsync(zb, 0, (size_t)N_NODES * H_HEADS * 4, stream);
    hipMemsetAsync(obuf, 0, (size_t)N_NODES * HC * 4, stream);
    set_minf_kernel<<<nh_blocks, 256, 0, stream>>>(mb);
    edge_max_kernel<<<emax_blocks, 256, 0, stream>>>(ei, asb, adb, mb);
    edge_accum_kernel<<<eacc_blocks, 256, 0, stream>>>(ei, asb, adb, mb, hbuf, zb, obuf);
    finalize_kernel<<<nhc_blocks, 256, 0, stream>>>(obuf, zb, b1);

    // ---------------- layer 2 ----------------
    gemm_tile<HC><<<gemm_blocks, 128, 0, stream>>>(obuf, W2, hbuf);
    alpha_kernel<<<nh_blocks, 256, 0, stream>>>(hbuf, as2, ad2, asb, adb);
    hipMemsetAsync(zb, 0, (size_t)N_NODES * H_HEADS * 4, stream);
    hipMemsetAsync(obuf, 0, (size_t)N_NODES * HC * 4, stream);  // h2 done; obuf reusable
    set_minf_kernel<<<nh_blocks, 256, 0, stream>>>(mb);
    edge_max_kernel<<<emax_blocks, 256, 0, stream>>>(ei, asb, adb, mb);
    edge_accum_kernel<<<eacc_blocks, 256, 0, stream>>>(ei, asb, adb, mb, hbuf, zb, obuf);
    finalize_kernel<<<nhc_blocks, 256, 0, stream>>>(obuf, zb, b2);

    // ---------------- pool + classifier ----------------
    hipMemsetAsync(sums, 0, (size_t)NUM_GRAPHS * HC * 4, stream);
    hipMemsetAsync(cnt, 0, (size_t)NUM_GRAPHS * 4, stream);
    pool_kernel<<<nhc_blocks, 256, 0, stream>>>(obuf, bat, sums, cnt);
    classifier_kernel<<<1, 64, 0, stream>>>(sums, cnt, Wc1, bc1, Wc2, bc2, outp);
}

// Round 2
// 1308.675 us; speedup vs baseline: 2.1751x; 2.1751x over previous
//
#include <hip/hip_runtime.h>
#include <math.h>

#define N_NODES 50000
#define E_EDGES 1600000
#define F_IN_DIM 256
#define H_HEADS 4
#define C_CH 32
#define HC 128
#define NUM_CLASSES 16
#define NUM_GRAPHS 64
#define ETOT (E_EDGES + N_NODES)
#define NEG_SLOPE 0.2f
#define SCAN_BLOCKS ((N_NODES + 255) / 256)   // 196

// ---- GEMM: Hout[n, 0:128] = X[n, 0:K] @ W[K, 128] ----
template <int K>
__global__ __launch_bounds__(128) void gemm_tile(const float* __restrict__ X,
                                                 const float* __restrict__ W,
                                                 float* __restrict__ Hout) {
    __shared__ float xs[32 * K];
    const int n0 = blockIdx.x * 32;
    const int t = threadIdx.x;  // output column
    for (int i = t; i < 32 * K; i += 128) {
        int r = i / K;
        int k = i - r * K;
        int n = n0 + r;
        xs[i] = (n < N_NODES) ? X[(size_t)n * K + k] : 0.f;
    }
    __syncthreads();
    float acc[32];
#pragma unroll
    for (int r = 0; r < 32; ++r) acc[r] = 0.f;
    for (int k = 0; k < K; k += 4) {
        float w0 = W[(k + 0) * HC + t];
        float w1 = W[(k + 1) * HC + t];
        float w2 = W[(k + 2) * HC + t];
        float w3 = W[(k + 3) * HC + t];
#pragma unroll
        for (int r = 0; r < 32; ++r) {
            const float4 xv = *reinterpret_cast<const float4*>(&xs[r * K + k]);
            acc[r] = fmaf(xv.x, w0,
                     fmaf(xv.y, w1,
                     fmaf(xv.z, w2,
                     fmaf(xv.w, w3, acc[r]))));
        }
    }
#pragma unroll
    for (int r = 0; r < 32; ++r) {
        int n = n0 + r;
        if (n < N_NODES) Hout[(size_t)n * HC + t] = acc[r];
    }
}

// ---- per-node attention logits: as/ad [N, H] ----
__global__ void alpha_kernel(const float* __restrict__ Hb,
                             const float* __restrict__ a_src,
                             const float* __restrict__ a_dst,
                             float* __restrict__ as, float* __restrict__ ad) {
    int i = blockIdx.x * blockDim.x + threadIdx.x;  // n*H + h
    if (i >= N_NODES * H_HEADS) return;
    int h = i & 3;
    const float* hp = Hb + (size_t)(i >> 2) * HC + h * C_CH;
    float ssum = 0.f, dsum = 0.f;
#pragma unroll
    for (int c = 0; c < C_CH; ++c) {
        float v = hp[c];
        ssum += v * a_src[h * C_CH + c];
        dsum += v * a_dst[h * C_CH + c];
    }
    as[i] = ssum;
    ad[i] = dsum;
}

// ================= CSR build (once per call) =================
__global__ void count_deg_kernel(const int* __restrict__ ei, int* __restrict__ deg) {
    int e = blockIdx.x * blockDim.x + threadIdx.x;
    if (e >= ETOT) return;
    int d = (e < E_EDGES) ? ei[E_EDGES + e] : (e - E_EDGES);
    atomicAdd(&deg[d], 1);
}

// per-block exclusive scan of deg -> excl, block sums -> bsum
__global__ __launch_bounds__(256) void scan_block_kernel(const int* __restrict__ deg,
                                                         int* __restrict__ excl,
                                                         int* __restrict__ bsum) {
    __shared__ int tmp[256];
    int i = blockIdx.x * 256 + threadIdx.x;
    int v = (i < N_NODES) ? deg[i] : 0;
    tmp[threadIdx.x] = v;
    __syncthreads();
    for (int off = 1; off < 256; off <<= 1) {
        int t = (threadIdx.x >= off) ? tmp[threadIdx.x - off] : 0;
        __syncthreads();
        tmp[threadIdx.x] += t;
        __syncthreads();
    }
    if (i < N_NODES) excl[i] = tmp[threadIdx.x] - v;
    if (threadIdx.x == 255) bsum[blockIdx.x] = tmp[255];
}

// exclusive scan of block sums (single block; SCAN_BLOCKS <= 256)
__global__ __launch_bounds__(256) void scan_tops_kernel(int* __restrict__ bsum) {
    __shared__ int tmp[256];
    int t = threadIdx.x;
    int v = (t < SCAN_BLOCKS) ? bsum[t] : 0;
    tmp[t] = v;
    __syncthreads();
    for (int off = 1; off < 256; off <<= 1) {
        int u = (t >= off) ? tmp[t - off] : 0;
        __syncthreads();
        tmp[t] += u;
        __syncthreads();
    }
    if (t < SCAN_BLOCKS) bsum[t] = tmp[t] - v;
}

__global__ void scan_add_kernel(int* __restrict__ excl, const int* __restrict__ bsum,
                                int* __restrict__ cursor) {
    int i = blockIdx.x * blockDim.x + threadIdx.x;
    if (i >= N_NODES) return;
    int s = excl[i] + bsum[i >> 8];
    excl[i] = s;     // row_start
    cursor[i] = s;   // scatter cursor
}

__global__ void scatter_edges_kernel(const int* __restrict__ ei,
                                     int* __restrict__ cursor,
                                     int* __restrict__ elist) {
    int e = blockIdx.x * blockDim.x + threadIdx.x;
    if (e >= ETOT) return;
    int s, d;
    if (e < E_EDGES) { s = ei[e]; d = ei[E_EDGES + e]; }
    else             { s = d = e - E_EDGES; }
    int pos = atomicAdd(&cursor[d], 1);
    elist[pos] = s;
}

// ============ fused gather GAT: online softmax + aggregate + bias + relu ============
__global__ __launch_bounds__(128) void gat_gather_kernel(const int* __restrict__ row_start,
                                                         const int* __restrict__ deg,
                                                         const int* __restrict__ elist,
                                                         const float* __restrict__ as,
                                                         const float* __restrict__ ad,
                                                         const float* __restrict__ Hb,
                                                         const float* __restrict__ bias,
                                                         float* __restrict__ out) {
    const int n = blockIdx.x;
    const int c = threadIdx.x;      // channel 0..127
    const int h = c >> 5;           // head
    const int row = row_start[n];
    const int len = deg[n];
    const float ad_n = ad[n * 4 + h];
    float m = -INFINITY, zs = 0.f, acc = 0.f;
    __shared__ int sbuf[128];
    for (int base = 0; base < len; base += 128) {
        int cl = min(128, len - base);
        if (c < cl) sbuf[c] = elist[row + base + c];
        __syncthreads();
        for (int j = 0; j < cl; ++j) {
            int s = sbuf[j];
            float ev = as[s * 4 + h] + ad_n;
            ev = ev > 0.f ? ev : ev * NEG_SLOPE;
            if (ev > m) {  // uniform within each 32-lane head group
                float sc = __expf(m - ev);  // first time: exp(-inf)=0
                acc *= sc;
                zs *= sc;
                m = ev;
            }
            float p = __expf(ev - m);
            zs += p;
            acc = fmaf(p, Hb[(size_t)s * HC + c], acc);
        }
        __syncthreads();
    }
    float v = acc / zs + bias[c];
    out[(size_t)n * HC + c] = v > 0.f ? v : 0.f;
}

// ---- global mean pool ----
__global__ void pool_kernel(const float* __restrict__ out,
                            const int* __restrict__ batch,
                            float* __restrict__ sums, float* __restrict__ cnt) {
    int i = blockIdx.x * blockDim.x + threadIdx.x;
    if (i >= N_NODES * HC) return;
    int n = i >> 7, c = i & 127;
    int g = batch[n];
    atomicAdd(&sums[(size_t)g * HC + c], out[i]);
    if (c == 0) atomicAdd(&cnt[g], 1.0f);
}

// ---- classifier ----
__global__ void classifier_kernel(const float* __restrict__ sums,
                                  const float* __restrict__ cnt,
                                  const float* __restrict__ Wc1,
                                  const float* __restrict__ bc1,
                                  const float* __restrict__ Wc2,
                                  const float* __restrict__ bc2,
                                  float* __restrict__ outp) {
    int g = threadIdx.x;
    if (g >= NUM_GRAPHS) return;
    float inv = 1.0f / cnt[g];
    float hidden[C_CH];
#pragma unroll 4
    for (int j = 0; j < C_CH; ++j) {
        float acc = bc1[j];
        for (int c = 0; c < HC; ++c)
            acc += (sums[g * HC + c] * inv) * Wc1[c * C_CH + j];
        hidden[j] = acc;
    }
    for (int k = 0; k < NUM_CLASSES; ++k) {
        float acc = bc2[k];
#pragma unroll
        for (int j = 0; j < C_CH; ++j) acc += hidden[j] * Wc2[j * NUM_CLASSES + k];
        outp[g * NUM_CLASSES + k] = 1.0f / (1.0f + __expf(-acc));
    }
}

extern "C" void kernel_launch(void* const* d_in, const int* in_sizes, int n_in,
                              void* d_out, int out_size, void* d_ws, size_t ws_size,
                              hipStream_t stream) {
    const float* x   = (const float*)d_in[0];
    const int*   ei  = (const int*)  d_in[1];
    const int*   bat = (const int*)  d_in[2];
    const float* W1  = (const float*)d_in[3];
    const float* as1 = (const float*)d_in[4];
    const float* ad1 = (const float*)d_in[5];
    const float* b1  = (const float*)d_in[6];
    const float* W2  = (const float*)d_in[7];
    const float* as2 = (const float*)d_in[8];
    const float* ad2 = (const float*)d_in[9];
    const float* b2  = (const float*)d_in[10];
    const float* Wc1 = (const float*)d_in[11];
    const float* bc1 = (const float*)d_in[12];
    const float* Wc2 = (const float*)d_in[13];
    const float* bc2 = (const float*)d_in[14];
    float* outp = (float*)d_out;

    char* ws = (char*)d_ws;
    float* hbuf = (float*)ws;  ws += (size_t)N_NODES * HC * 4;
    float* obuf = (float*)ws;  ws += (size_t)N_NODES * HC * 4;
    float* asb  = (float*)ws;  ws += (size_t)N_NODES * H_HEADS * 4;
    float* adb  = (float*)ws;  ws += (size_t)N_NODES * H_HEADS * 4;
    int* elist    = (int*)ws;  ws += (size_t)ETOT * 4;
    int* row_start= (int*)ws;  ws += (size_t)N_NODES * 4;
    int* degb     = (int*)ws;  ws += (size_t)N_NODES * 4;
    int* cursor   = (int*)ws;  ws += (size_t)N_NODES * 4;
    int* bsum     = (int*)ws;  ws += 256 * 4;
    float* sums = (float*)ws;  ws += (size_t)NUM_GRAPHS * HC * 4;
    float* cnt  = (float*)ws;  ws += (size_t)NUM_GRAPHS * 4;

    const int nh_blocks  = (N_NODES * H_HEADS + 255) / 256;
    const int n_blocks   = (N_NODES + 255) / 256;
    const int e_blocks   = (ETOT + 255) / 256;
    const int nhc_blocks = (N_NODES * HC + 255) / 256;
    const int gemm_blocks = (N_NODES + 31) / 32;

    // ---------------- CSR build (shared by both layers) ----------------
    hipMemsetAsync(degb, 0, (size_t)N_NODES * 4, stream);
    count_deg_kernel<<<e_blocks, 256, 0, stream>>>(ei, degb);
    scan_block_kernel<<<SCAN_BLOCKS, 256, 0, stream>>>(degb, row_start, bsum);
    scan_tops_kernel<<<1, 256, 0, stream>>>(bsum);
    scan_add_kernel<<<n_blocks, 256, 0, stream>>>(row_start, bsum, cursor);
    scatter_edges_kernel<<<e_blocks, 256, 0, stream>>>(ei, cursor, elist);

    // ---------------- layer 1 ----------------
    gemm_tile<F_IN_DIM><<<gemm_blocks, 128, 0, stream>>>(x, W1, hbuf);
    alpha_kernel<<<nh_blocks, 256, 0, stream>>>(hbuf, as1, ad1, asb, adb);
    gat_gather_kernel<<<N_NODES, 128, 0, stream>>>(row_start, degb, elist,
                                                   asb, adb, hbuf, b1, obuf);

    // ---------------- layer 2 ----------------
    gemm_tile<HC><<<gemm_blocks, 128, 0, stream>>>(obuf, W2, hbuf);
    alpha_kernel<<<nh_blocks, 256, 0, stream>>>(hbuf, as2, ad2, asb, adb);
    gat_gather_kernel<<<N_NODES, 128, 0, stream>>>(row_start, degb, elist,
                                                   asb, adb, hbuf, b2, obuf);

    // ---------------- pool + classifier ----------------
    hipMemsetAsync(sums, 0, (size_t)NUM_GRAPHS * HC * 4, stream);
    hipMemsetAsync(cnt, 0, (size_t)NUM_GRAPHS * 4, stream);
    pool_kernel<<<nhc_blocks, 256, 0, stream>>>(obuf, bat, sums, cnt);
    classifier_kernel<<<1, 64, 0, stream>>>(sums, cnt, Wc1, bc1, Wc2, bc2, outp);
}

// Round 3
// 947.220 us; speedup vs baseline: 3.0051x; 1.3816x over previous
//
#include <hip/hip_runtime.h>
#include <math.h>

#define N_NODES 50000
#define E_EDGES 1600000
#define F_IN_DIM 256
#define H_HEADS 4
#define C_CH 32
#define HC 128
#define NUM_CLASSES 16
#define NUM_GRAPHS 64
#define ETOT (E_EDGES + N_NODES)
#define NEG_SLOPE 0.2f
#define SCAN_BLOCKS ((N_NODES + 255) / 256)   // 196
#define POOL_SPLIT 8

// ---- GEMM: Hout[n, 0:128] = X[n, 0:K] @ W[K, 128] ----
template <int K>
__global__ __launch_bounds__(128) void gemm_tile(const float* __restrict__ X,
                                                 const float* __restrict__ W,
                                                 float* __restrict__ Hout) {
    __shared__ float xs[32 * K];
    const int n0 = blockIdx.x * 32;
    const int t = threadIdx.x;  // output column
    for (int i = t; i < 32 * K; i += 128) {
        int r = i / K;
        int k = i - r * K;
        int n = n0 + r;
        xs[i] = (n < N_NODES) ? X[(size_t)n * K + k] : 0.f;
    }
    __syncthreads();
    float acc[32];
#pragma unroll
    for (int r = 0; r < 32; ++r) acc[r] = 0.f;
    for (int k = 0; k < K; k += 4) {
        float w0 = W[(k + 0) * HC + t];
        float w1 = W[(k + 1) * HC + t];
        float w2 = W[(k + 2) * HC + t];
        float w3 = W[(k + 3) * HC + t];
#pragma unroll
        for (int r = 0; r < 32; ++r) {
            const float4 xv = *reinterpret_cast<const float4*>(&xs[r * K + k]);
            acc[r] = fmaf(xv.x, w0,
                     fmaf(xv.y, w1,
                     fmaf(xv.z, w2,
                     fmaf(xv.w, w3, acc[r]))));
        }
    }
#pragma unroll
    for (int r = 0; r < 32; ++r) {
        int n = n0 + r;
        if (n < N_NODES) Hout[(size_t)n * HC + t] = acc[r];
    }
}

// ---- per-node attention logits: as/ad [N, H] ----
__global__ void alpha_kernel(const float* __restrict__ Hb,
                             const float* __restrict__ a_src,
                             const float* __restrict__ a_dst,
                             float* __restrict__ as, float* __restrict__ ad) {
    int i = blockIdx.x * blockDim.x + threadIdx.x;  // n*H + h
    if (i >= N_NODES * H_HEADS) return;
    int h = i & 3;
    const float* hp = Hb + (size_t)(i >> 2) * HC + h * C_CH;
    float ssum = 0.f, dsum = 0.f;
#pragma unroll
    for (int c = 0; c < C_CH; ++c) {
        float v = hp[c];
        ssum += v * a_src[h * C_CH + c];
        dsum += v * a_dst[h * C_CH + c];
    }
    as[i] = ssum;
    ad[i] = dsum;
}

// ================= CSR build (once per call) =================
__global__ void count_deg_kernel(const int* __restrict__ ei, int* __restrict__ deg) {
    int e = blockIdx.x * blockDim.x + threadIdx.x;
    if (e >= ETOT) return;
    int d = (e < E_EDGES) ? ei[E_EDGES + e] : (e - E_EDGES);
    atomicAdd(&deg[d], 1);
}

// per-block exclusive scan of deg -> excl, block sums -> bsum
__global__ __launch_bounds__(256) void scan_block_kernel(const int* __restrict__ deg,
                                                         int* __restrict__ excl,
                                                         int* __restrict__ bsum) {
    __shared__ int tmp[256];
    int i = blockIdx.x * 256 + threadIdx.x;
    int v = (i < N_NODES) ? deg[i] : 0;
    tmp[threadIdx.x] = v;
    __syncthreads();
    for (int off = 1; off < 256; off <<= 1) {
        int t = (threadIdx.x >= off) ? tmp[threadIdx.x - off] : 0;
        __syncthreads();
        tmp[threadIdx.x] += t;
        __syncthreads();
    }
    if (i < N_NODES) excl[i] = tmp[threadIdx.x] - v;
    if (threadIdx.x == 255) bsum[blockIdx.x] = tmp[255];
}

// exclusive scan of block sums (single block; SCAN_BLOCKS <= 256)
__global__ __launch_bounds__(256) void scan_tops_kernel(int* __restrict__ bsum) {
    __shared__ int tmp[256];
    int t = threadIdx.x;
    int v = (t < SCAN_BLOCKS) ? bsum[t] : 0;
    tmp[t] = v;
    __syncthreads();
    for (int off = 1; off < 256; off <<= 1) {
        int u = (t >= off) ? tmp[t - off] : 0;
        __syncthreads();
        tmp[t] += u;
        __syncthreads();
    }
    if (t < SCAN_BLOCKS) bsum[t] = tmp[t] - v;
}

__global__ void scan_add_kernel(int* __restrict__ excl, const int* __restrict__ bsum,
                                int* __restrict__ cursor) {
    int i = blockIdx.x * blockDim.x + threadIdx.x;
    if (i >= N_NODES) return;
    int s = excl[i] + bsum[i >> 8];
    excl[i] = s;     // row_start
    cursor[i] = s;   // scatter cursor
}

__global__ void scatter_edges_kernel(const int* __restrict__ ei,
                                     int* __restrict__ cursor,
                                     int* __restrict__ elist) {
    int e = blockIdx.x * blockDim.x + threadIdx.x;
    if (e >= ETOT) return;
    int s, d;
    if (e < E_EDGES) { s = ei[e]; d = ei[E_EDGES + e]; }
    else             { s = d = e - E_EDGES; }
    int pos = atomicAdd(&cursor[d], 1);
    elist[pos] = s;
}

// ============ fused gather GAT: online softmax + aggregate + bias + relu ============
__global__ __launch_bounds__(128) void gat_gather_kernel(const int* __restrict__ row_start,
                                                         const int* __restrict__ deg,
                                                         const int* __restrict__ elist,
                                                         const float* __restrict__ as,
                                                         const float* __restrict__ ad,
                                                         const float* __restrict__ Hb,
                                                         const float* __restrict__ bias,
                                                         float* __restrict__ out) {
    const int n = blockIdx.x;
    const int c = threadIdx.x;      // channel 0..127
    const int h = c >> 5;           // head
    const int row = row_start[n];
    const int len = deg[n];
    const float ad_n = ad[n * 4 + h];
    float m = -INFINITY, zs = 0.f, acc = 0.f;
    __shared__ int sbuf[128];
    for (int base = 0; base < len; base += 128) {
        int cl = min(128, len - base);
        if (c < cl) sbuf[c] = elist[row + base + c];
        __syncthreads();
        for (int j = 0; j < cl; ++j) {
            int s = sbuf[j];
            float ev = as[s * 4 + h] + ad_n;
            ev = ev > 0.f ? ev : ev * NEG_SLOPE;
            if (ev > m) {  // uniform within each 32-lane head group
                float sc = __expf(m - ev);  // first time: exp(-inf)=0
                acc *= sc;
                zs *= sc;
                m = ev;
            }
            float p = __expf(ev - m);
            zs += p;
            acc = fmaf(p, Hb[(size_t)s * HC + c], acc);
        }
        __syncthreads();
    }
    float v = acc / zs + bias[c];
    out[(size_t)n * HC + c] = v > 0.f ? v : 0.f;
}

// ---- graph boundaries via binary search on sorted batch ----
// gstart[g] = first index n with batch[n] >= g ; gstart[NUM_GRAPHS] = N
__global__ void boundary_kernel(const int* __restrict__ batch,
                                int* __restrict__ gstart,
                                float* __restrict__ cntf) {
    int g = threadIdx.x;
    if (g <= NUM_GRAPHS) {
        int lo = 0, hi = N_NODES;
        while (lo < hi) {
            int mid = (lo + hi) >> 1;
            if (batch[mid] < g) lo = mid + 1; else hi = mid;
        }
        gstart[g] = lo;
    }
    __syncthreads();
    if (g < NUM_GRAPHS) cntf[g] = (float)(gstart[g + 1] - gstart[g]);
}

// ---- pool: 8 blocks per graph, register accumulation, 1 atomic per thread ----
__global__ __launch_bounds__(128) void pool_seg_kernel(const float* __restrict__ out,
                                                       const int* __restrict__ gstart,
                                                       float* __restrict__ sums) {
    const int g = blockIdx.x >> 3;
    const int split = blockIdx.x & 7;
    const int c = threadIdx.x;
    const int start = gstart[g], end = gstart[g + 1];
    const int len = end - start;
    const int chunk = (len + POOL_SPLIT - 1) / POOL_SPLIT;
    const int s0 = start + split * chunk;
    const int s1 = min(s0 + chunk, end);
    float acc = 0.f;
    for (int n = s0; n < s1; ++n) acc += out[(size_t)n * HC + c];
    if (s0 < s1) atomicAdd(&sums[g * HC + c], acc);
}

// ---- classifier ----
__global__ void classifier_kernel(const float* __restrict__ sums,
                                  const float* __restrict__ cnt,
                                  const float* __restrict__ Wc1,
                                  const float* __restrict__ bc1,
                                  const float* __restrict__ Wc2,
                                  const float* __restrict__ bc2,
                                  float* __restrict__ outp) {
    int g = threadIdx.x;
    if (g >= NUM_GRAPHS) return;
    float inv = 1.0f / cnt[g];
    float hidden[C_CH];
#pragma unroll 4
    for (int j = 0; j < C_CH; ++j) {
        float acc = bc1[j];
        for (int c = 0; c < HC; ++c)
            acc += (sums[g * HC + c] * inv) * Wc1[c * C_CH + j];
        hidden[j] = acc;
    }
    for (int k = 0; k < NUM_CLASSES; ++k) {
        float acc = bc2[k];
#pragma unroll
        for (int j = 0; j < C_CH; ++j) acc += hidden[j] * Wc2[j * NUM_CLASSES + k];
        outp[g * NUM_CLASSES + k] = 1.0f / (1.0f + __expf(-acc));
    }
}

extern "C" void kernel_launch(void* const* d_in, const int* in_sizes, int n_in,
                              void* d_out, int out_size, void* d_ws, size_t ws_size,
                              hipStream_t stream) {
    const float* x   = (const float*)d_in[0];
    const int*   ei  = (const int*)  d_in[1];
    const int*   bat = (const int*)  d_in[2];
    const float* W1  = (const float*)d_in[3];
    const float* as1 = (const float*)d_in[4];
    const float* ad1 = (const float*)d_in[5];
    const float* b1  = (const float*)d_in[6];
    const float* W2  = (const float*)d_in[7];
    const float* as2 = (const float*)d_in[8];
    const float* ad2 = (const float*)d_in[9];
    const float* b2  = (const float*)d_in[10];
    const float* Wc1 = (const float*)d_in[11];
    const float* bc1 = (const float*)d_in[12];
    const float* Wc2 = (const float*)d_in[13];
    const float* bc2 = (const float*)d_in[14];
    float* outp = (float*)d_out;

    char* ws = (char*)d_ws;
    float* hbuf = (float*)ws;  ws += (size_t)N_NODES * HC * 4;
    float* obuf = (float*)ws;  ws += (size_t)N_NODES * HC * 4;
    float* asb  = (float*)ws;  ws += (size_t)N_NODES * H_HEADS * 4;
    float* adb  = (float*)ws;  ws += (size_t)N_NODES * H_HEADS * 4;
    int* elist    = (int*)ws;  ws += (size_t)ETOT * 4;
    int* row_start= (int*)ws;  ws += (size_t)N_NODES * 4;
    int* degb     = (int*)ws;  ws += (size_t)N_NODES * 4;
    int* cursor   = (int*)ws;  ws += (size_t)N_NODES * 4;
    int* bsum     = (int*)ws;  ws += 256 * 4;
    int* gstart   = (int*)ws;  ws += (NUM_GRAPHS + 1) * 4;
    float* sums = (float*)ws;  ws += (size_t)NUM_GRAPHS * HC * 4;
    float* cnt  = (float*)ws;  ws += (size_t)NUM_GRAPHS * 4;

    const int nh_blocks  = (N_NODES * H_HEADS + 255) / 256;
    const int n_blocks   = (N_NODES + 255) / 256;
    const int e_blocks   = (ETOT + 255) / 256;
    const int gemm_blocks = (N_NODES + 31) / 32;

    // ---------------- CSR build (shared by both layers) ----------------
    hipMemsetAsync(degb, 0, (size_t)N_NODES * 4, stream);
    count_deg_kernel<<<e_blocks, 256, 0, stream>>>(ei, degb);
    scan_block_kernel<<<SCAN_BLOCKS, 256, 0, stream>>>(degb, row_start, bsum);
    scan_tops_kernel<<<1, 256, 0, stream>>>(bsum);
    scan_add_kernel<<<n_blocks, 256, 0, stream>>>(row_start, bsum, cursor);
    scatter_edges_kernel<<<e_blocks, 256, 0, stream>>>(ei, cursor, elist);

    // ---------------- layer 1 ----------------
    gemm_tile<F_IN_DIM><<<gemm_blocks, 128, 0, stream>>>(x, W1, hbuf);
    alpha_kernel<<<nh_blocks, 256, 0, stream>>>(hbuf, as1, ad1, asb, adb);
    gat_gather_kernel<<<N_NODES, 128, 0, stream>>>(row_start, degb, elist,
                                                   asb, adb, hbuf, b1, obuf);

    // ---------------- layer 2 ----------------
    gemm_tile<HC><<<gemm_blocks, 128, 0, stream>>>(obuf, W2, hbuf);
    alpha_kernel<<<nh_blocks, 256, 0, stream>>>(hbuf, as2, ad2, asb, adb);
    gat_gather_kernel<<<N_NODES, 128, 0, stream>>>(row_start, degb, elist,
                                                   asb, adb, hbuf, b2, obuf);

    // ---------------- pool + classifier ----------------
    boundary_kernel<<<1, 128, 0, stream>>>(bat, gstart, cnt);
    hipMemsetAsync(sums, 0, (size_t)NUM_GRAPHS * HC * 4, stream);
    pool_seg_kernel<<<NUM_GRAPHS * POOL_SPLIT, 128, 0, stream>>>(obuf, gstart, sums);
    classifier_kernel<<<1, 64, 0, stream>>>(sums, cnt, Wc1, bc1, Wc2, bc2, outp);
}

// Round 5
// 807.233 us; speedup vs baseline: 3.5263x; 1.1734x over previous
//
#include <hip/hip_runtime.h>
#include <math.h>

#define N_NODES 50000
#define E_EDGES 1600000
#define F_IN_DIM 256
#define H_HEADS 4
#define C_CH 32
#define HC 128
#define NUM_CLASSES 16
#define NUM_GRAPHS 64
#define ETOT (E_EDGES + N_NODES)
#define NEG_SLOPE 0.2f
#define SCAN_BLOCKS ((N_NODES + 255) / 256)   // 196
#define POOL_SPLIT 8

// ---- register-blocked GEMM: Hout[n, 0:128] = X[n, 0:K] @ W[K, 128] ----
// 256 threads; BM=64 rows; per-thread 8 rows x 4 cols; K chunked by 32.
// x-tile transposed in LDS (xs[k][row], pad 68 for 16B-aligned float4 rows).
template <int K>
__global__ __launch_bounds__(256) void gemm_rb(const float* __restrict__ X,
                                               const float* __restrict__ W,
                                               float* __restrict__ Hout) {
    __shared__ float xs[32][68];
    const int n0 = blockIdx.x * 64;
    const int tid = threadIdx.x;
    const int rg = tid >> 5;       // 0..7  -> rows rg*8 .. rg*8+7
    const int cg = tid & 31;       // 0..31 -> cols cg*4 .. cg*4+3
    const int r0 = rg * 8;
    const int c0 = cg * 4;
    float acc[8][4];
#pragma unroll
    for (int i = 0; i < 8; ++i)
#pragma unroll
        for (int j = 0; j < 4; ++j) acc[i][j] = 0.f;

    for (int k0 = 0; k0 < K; k0 += 32) {
        __syncthreads();
        // stage 64 rows x 32 ks of X, transposed: 2 float4 loads per thread
#pragma unroll
        for (int L = tid; L < 512; L += 256) {
            int row = L >> 3;
            int kq = L & 7;
            int n = n0 + row;
            float4 v = make_float4(0.f, 0.f, 0.f, 0.f);
            if (n < N_NODES)
                v = *reinterpret_cast<const float4*>(&X[(size_t)n * K + k0 + kq * 4]);
            xs[kq * 4 + 0][row] = v.x;
            xs[kq * 4 + 1][row] = v.y;
            xs[kq * 4 + 2][row] = v.z;
            xs[kq * 4 + 3][row] = v.w;
        }
        __syncthreads();
#pragma unroll 8
        for (int k = 0; k < 32; ++k) {
            const float4 w = *reinterpret_cast<const float4*>(&W[(size_t)(k0 + k) * HC + c0]);
            const float4 xa = *reinterpret_cast<const float4*>(&xs[k][r0]);
            const float4 xb = *reinterpret_cast<const float4*>(&xs[k][r0 + 4]);
            acc[0][0] = fmaf(xa.x, w.x, acc[0][0]);
            acc[0][1] = fmaf(xa.x, w.y, acc[0][1]);
            acc[0][2] = fmaf(xa.x, w.z, acc[0][2]);
            acc[0][3] = fmaf(xa.x, w.w, acc[0][3]);
            acc[1][0] = fmaf(xa.y, w.x, acc[1][0]);
            acc[1][1] = fmaf(xa.y, w.y, acc[1][1]);
            acc[1][2] = fmaf(xa.y, w.z, acc[1][2]);
            acc[1][3] = fmaf(xa.y, w.w, acc[1][3]);
            acc[2][0] = fmaf(xa.z, w.x, acc[2][0]);
            acc[2][1] = fmaf(xa.z, w.y, acc[2][1]);
            acc[2][2] = fmaf(xa.z, w.z, acc[2][2]);
            acc[2][3] = fmaf(xa.z, w.w, acc[2][3]);
            acc[3][0] = fmaf(xa.w, w.x, acc[3][0]);
            acc[3][1] = fmaf(xa.w, w.y, acc[3][1]);
            acc[3][2] = fmaf(xa.w, w.z, acc[3][2]);
            acc[3][3] = fmaf(xa.w, w.w, acc[3][3]);
            acc[4][0] = fmaf(xb.x, w.x, acc[4][0]);
            acc[4][1] = fmaf(xb.x, w.y, acc[4][1]);
            acc[4][2] = fmaf(xb.x, w.z, acc[4][2]);
            acc[4][3] = fmaf(xb.x, w.w, acc[4][3]);
            acc[5][0] = fmaf(xb.y, w.x, acc[5][0]);
            acc[5][1] = fmaf(xb.y, w.y, acc[5][1]);
            acc[5][2] = fmaf(xb.y, w.z, acc[5][2]);
            acc[5][3] = fmaf(xb.y, w.w, acc[5][3]);
            acc[6][0] = fmaf(xb.z, w.x, acc[6][0]);
            acc[6][1] = fmaf(xb.z, w.y, acc[6][1]);
            acc[6][2] = fmaf(xb.z, w.z, acc[6][2]);
            acc[6][3] = fmaf(xb.z, w.w, acc[6][3]);
            acc[7][0] = fmaf(xb.w, w.x, acc[7][0]);
            acc[7][1] = fmaf(xb.w, w.y, acc[7][1]);
            acc[7][2] = fmaf(xb.w, w.z, acc[7][2]);
            acc[7][3] = fmaf(xb.w, w.w, acc[7][3]);
        }
    }
#pragma unroll
    for (int i = 0; i < 8; ++i) {
        int n = n0 + r0 + i;
        if (n < N_NODES)
            *reinterpret_cast<float4*>(&Hout[(size_t)n * HC + c0]) =
                make_float4(acc[i][0], acc[i][1], acc[i][2], acc[i][3]);
    }
}

// ---- per-node attention logits: as/ad [N, H] ----
__global__ void alpha_kernel(const float* __restrict__ Hb,
                             const float* __restrict__ a_src,
                             const float* __restrict__ a_dst,
                             float* __restrict__ as, float* __restrict__ ad) {
    int i = blockIdx.x * blockDim.x + threadIdx.x;  // n*H + h
    if (i >= N_NODES * H_HEADS) return;
    int h = i & 3;
    const float* hp = Hb + (size_t)(i >> 2) * HC + h * C_CH;
    float ssum = 0.f, dsum = 0.f;
#pragma unroll
    for (int c = 0; c < C_CH; ++c) {
        float v = hp[c];
        ssum += v * a_src[h * C_CH + c];
        dsum += v * a_dst[h * C_CH + c];
    }
    as[i] = ssum;
    ad[i] = dsum;
}

// ================= CSR build (once per call) =================
__global__ void count_deg_kernel(const int* __restrict__ ei, int* __restrict__ deg) {
    int e = blockIdx.x * blockDim.x + threadIdx.x;
    if (e >= ETOT) return;
    int d = (e < E_EDGES) ? ei[E_EDGES + e] : (e - E_EDGES);
    atomicAdd(&deg[d], 1);
}

__global__ __launch_bounds__(256) void scan_block_kernel(const int* __restrict__ deg,
                                                         int* __restrict__ excl,
                                                         int* __restrict__ bsum) {
    __shared__ int tmp[256];
    int i = blockIdx.x * 256 + threadIdx.x;
    int v = (i < N_NODES) ? deg[i] : 0;
    tmp[threadIdx.x] = v;
    __syncthreads();
    for (int off = 1; off < 256; off <<= 1) {
        int t = (threadIdx.x >= off) ? tmp[threadIdx.x - off] : 0;
        __syncthreads();
        tmp[threadIdx.x] += t;
        __syncthreads();
    }
    if (i < N_NODES) excl[i] = tmp[threadIdx.x] - v;
    if (threadIdx.x == 255) bsum[blockIdx.x] = tmp[255];
}

__global__ __launch_bounds__(256) void scan_tops_kernel(int* __restrict__ bsum) {
    __shared__ int tmp[256];
    int t = threadIdx.x;
    int v = (t < SCAN_BLOCKS) ? bsum[t] : 0;
    tmp[t] = v;
    __syncthreads();
    for (int off = 1; off < 256; off <<= 1) {
        int u = (t >= off) ? tmp[t - off] : 0;
        __syncthreads();
        tmp[t] += u;
        __syncthreads();
    }
    if (t < SCAN_BLOCKS) bsum[t] = tmp[t] - v;
}

__global__ void scan_add_kernel(int* __restrict__ excl, const int* __restrict__ bsum,
                                int* __restrict__ cursor) {
    int i = blockIdx.x * blockDim.x + threadIdx.x;
    if (i >= N_NODES) return;
    int s = excl[i] + bsum[i >> 8];
    excl[i] = s;     // row_start
    cursor[i] = s;   // scatter cursor
}

__global__ void scatter_edges_kernel(const int* __restrict__ ei,
                                     int* __restrict__ cursor,
                                     int* __restrict__ elist) {
    int e = blockIdx.x * blockDim.x + threadIdx.x;
    if (e >= ETOT) return;
    int s, d;
    if (e < E_EDGES) { s = ei[e]; d = ei[E_EDGES + e]; }
    else             { s = d = e - E_EDGES; }
    int pos = atomicAdd(&cursor[d], 1);
    elist[pos] = s;
}

// ============ fused gather GAT: online softmax + aggregate + bias + relu ============
__global__ __launch_bounds__(128) void gat_gather_kernel(const int* __restrict__ row_start,
                                                         const int* __restrict__ deg,
                                                         const int* __restrict__ elist,
                                                         const float* __restrict__ as,
                                                         const float* __restrict__ ad,
                                                         const float* __restrict__ Hb,
                                                         const float* __restrict__ bias,
                                                         float* __restrict__ out) {
    const int n = blockIdx.x;
    const int c = threadIdx.x;      // channel 0..127
    const int h = c >> 5;           // head
    const int row = row_start[n];
    const int len = deg[n];
    const float ad_n = ad[n * 4 + h];
    float m = -INFINITY, zs = 0.f, acc = 0.f;
    __shared__ int sbuf[128];
    for (int base = 0; base < len; base += 128) {
        int cl = min(128, len - base);
        if (c < cl) sbuf[c] = elist[row + base + c];
        __syncthreads();
        for (int j = 0; j < cl; ++j) {
            int s = sbuf[j];
            float ev = as[s * 4 + h] + ad_n;
            ev = ev > 0.f ? ev : ev * NEG_SLOPE;
            if (ev > m) {  // uniform within each 32-lane head group
                float sc = __expf(m - ev);  // first time: exp(-inf)=0
                acc *= sc;
                zs *= sc;
                m = ev;
            }
            float p = __expf(ev - m);
            zs += p;
            acc = fmaf(p, Hb[(size_t)s * HC + c], acc);
        }
        __syncthreads();
    }
    float v = acc / zs + bias[c];
    out[(size_t)n * HC + c] = v > 0.f ? v : 0.f;
}

// ---- graph boundaries via binary search on sorted batch ----
__global__ void boundary_kernel(const int* __restrict__ batch,
                                int* __restrict__ gstart,
                                float* __restrict__ cntf) {
    int g = threadIdx.x;
    if (g <= NUM_GRAPHS) {
        int lo = 0, hi = N_NODES;
        while (lo < hi) {
            int mid = (lo + hi) >> 1;
            if (batch[mid] < g) lo = mid + 1; else hi = mid;
        }
        gstart[g] = lo;
    }
    __syncthreads();
    if (g < NUM_GRAPHS) cntf[g] = (float)(gstart[g + 1] - gstart[g]);
}

// ---- pool: 8 blocks per graph, register accumulation, 1 atomic per thread ----
__global__ __launch_bounds__(128) void pool_seg_kernel(const float* __restrict__ out,
                                                       const int* __restrict__ gstart,
                                                       float* __restrict__ sums) {
    const int g = blockIdx.x >> 3;
    const int split = blockIdx.x & 7;
    const int c = threadIdx.x;
    const int start = gstart[g], end = gstart[g + 1];
    const int len = end - start;
    const int chunk = (len + POOL_SPLIT - 1) / POOL_SPLIT;
    const int s0 = start + split * chunk;
    const int s1 = min(s0 + chunk, end);
    float acc = 0.f;
    for (int n = s0; n < s1; ++n) acc += out[(size_t)n * HC + c];
    if (s0 < s1) atomicAdd(&sums[g * HC + c], acc);
}

// ---- classifier ----
__global__ void classifier_kernel(const float* __restrict__ sums,
                                  const float* __restrict__ cnt,
                                  const float* __restrict__ Wc1,
                                  const float* __restrict__ bc1,
                                  const float* __restrict__ Wc2,
                                  const float* __restrict__ bc2,
                                  float* __restrict__ outp) {
    int g = threadIdx.x;
    if (g >= NUM_GRAPHS) return;
    float inv = 1.0f / cnt[g];
    float hidden[C_CH];
#pragma unroll 4
    for (int j = 0; j < C_CH; ++j) {
        float acc = bc1[j];
        for (int c = 0; c < HC; ++c)
            acc += (sums[g * HC + c] * inv) * Wc1[c * C_CH + j];
        hidden[j] = acc;
    }
    for (int k = 0; k < NUM_CLASSES; ++k) {
        float acc = bc2[k];
#pragma unroll
        for (int j = 0; j < C_CH; ++j) acc += hidden[j] * Wc2[j * NUM_CLASSES + k];
        outp[g * NUM_CLASSES + k] = 1.0f / (1.0f + __expf(-acc));
    }
}

extern "C" void kernel_launch(void* const* d_in, const int* in_sizes, int n_in,
                              void* d_out, int out_size, void* d_ws, size_t ws_size,
                              hipStream_t stream) {
    const float* x   = (const float*)d_in[0];
    const int*   ei  = (const int*)  d_in[1];
    const int*   bat = (const int*)  d_in[2];
    const float* W1  = (const float*)d_in[3];
    const float* as1 = (const float*)d_in[4];
    const float* ad1 = (const float*)d_in[5];
    const float* b1  = (const float*)d_in[6];
    const float* W2  = (const float*)d_in[7];
    const float* as2 = (const float*)d_in[8];
    const float* ad2 = (const float*)d_in[9];
    const float* b2  = (const float*)d_in[10];
    const float* Wc1 = (const float*)d_in[11];
    const float* bc1 = (const float*)d_in[12];
    const float* Wc2 = (const float*)d_in[13];
    const float* bc2 = (const float*)d_in[14];
    float* outp = (float*)d_out;

    char* ws = (char*)d_ws;
    float* hbuf = (float*)ws;  ws += (size_t)N_NODES * HC * 4;
    float* obuf = (float*)ws;  ws += (size_t)N_NODES * HC * 4;
    float* asb  = (float*)ws;  ws += (size_t)N_NODES * H_HEADS * 4;
    float* adb  = (float*)ws;  ws += (size_t)N_NODES * H_HEADS * 4;
    int* elist    = (int*)ws;  ws += (size_t)ETOT * 4;
    int* row_start= (int*)ws;  ws += (size_t)N_NODES * 4;
    int* degb     = (int*)ws;  ws += (size_t)N_NODES * 4;
    int* cursor   = (int*)ws;  ws += (size_t)N_NODES * 4;
    int* bsum     = (int*)ws;  ws += 256 * 4;
    int* gstart   = (int*)ws;  ws += (NUM_GRAPHS + 1) * 4;
    float* sums = (float*)ws;  ws += (size_t)NUM_GRAPHS * HC * 4;
    float* cnt  = (float*)ws;  ws += (size_t)NUM_GRAPHS * 4;

    const int nh_blocks  = (N_NODES * H_HEADS + 255) / 256;
    const int n_blocks   = (N_NODES + 255) / 256;
    const int e_blocks   = (ETOT + 255) / 256;
    const int gemm_blocks = (N_NODES + 63) / 64;

    // ---------------- CSR build (shared by both layers) ----------------
    hipMemsetAsync(degb, 0, (size_t)N_NODES * 4, stream);
    count_deg_kernel<<<e_blocks, 256, 0, stream>>>(ei, degb);
    scan_block_kernel<<<SCAN_BLOCKS, 256, 0, stream>>>(degb, row_start, bsum);
    scan_tops_kernel<<<1, 256, 0, stream>>>(bsum);
    scan_add_kernel<<<n_blocks, 256, 0, stream>>>(row_start, bsum, cursor);
    scatter_edges_kernel<<<e_blocks, 256, 0, stream>>>(ei, cursor, elist);

    // ---------------- layer 1 ----------------
    gemm_rb<F_IN_DIM><<<gemm_blocks, 256, 0, stream>>>(x, W1, hbuf);
    alpha_kernel<<<nh_blocks, 256, 0, stream>>>(hbuf, as1, ad1, asb, adb);
    gat_gather_kernel<<<N_NODES, 128, 0, stream>>>(row_start, degb, elist,
                                                   asb, adb, hbuf, b1, obuf);

    // ---------------- layer 2 ----------------
    gemm_rb<HC><<<gemm_blocks, 256, 0, stream>>>(obuf, W2, hbuf);
    alpha_kernel<<<nh_blocks, 256, 0, stream>>>(hbuf, as2, ad2, asb, adb);
    gat_gather_kernel<<<N_NODES, 128, 0, stream>>>(row_start, degb, elist,
                                                   asb, adb, hbuf, b2, obuf);

    // ---------------- pool + classifier ----------------
    boundary_kernel<<<1, 128, 0, stream>>>(bat, gstart, cnt);
    hipMemsetAsync(sums, 0, (size_t)NUM_GRAPHS * HC * 4, stream);
    pool_seg_kernel<<<NUM_GRAPHS * POOL_SPLIT, 128, 0, stream>>>(obuf, gstart, sums);
    classifier_kernel<<<1, 64, 0, stream>>>(sums, cnt, Wc1, bc1, Wc2, bc2, outp);
}

// Round 8
// 782.467 us; speedup vs baseline: 3.6379x; 1.0317x over previous
//
#include <hip/hip_runtime.h>
#include <math.h>

#define N_NODES 50000
#define E_EDGES 1600000
#define F_IN_DIM 256
#define H_HEADS 4
#define C_CH 32
#define HC 128
#define NUM_CLASSES 16
#define NUM_GRAPHS 64
#define ETOT (E_EDGES + N_NODES)
#define NEG_SLOPE 0.2f
#define SCAN_BLOCKS ((N_NODES + 255) / 256)   // 196
#define POOL_SPLIT 8

// ---- register-blocked GEMM: Hout[n, 0:128] = X[n, 0:K] @ W[K, 128] ----
template <int K>
__global__ __launch_bounds__(256) void gemm_rb(const float* __restrict__ X,
                                               const float* __restrict__ W,
                                               float* __restrict__ Hout) {
    __shared__ float xs[32][68];
    const int n0 = blockIdx.x * 64;
    const int tid = threadIdx.x;
    const int rg = tid >> 5;       // 0..7  -> rows rg*8 .. rg*8+7
    const int cg = tid & 31;       // 0..31 -> cols cg*4 .. cg*4+3
    const int r0 = rg * 8;
    const int c0 = cg * 4;
    float acc[8][4];
#pragma unroll
    for (int i = 0; i < 8; ++i)
#pragma unroll
        for (int j = 0; j < 4; ++j) acc[i][j] = 0.f;

    for (int k0 = 0; k0 < K; k0 += 32) {
        __syncthreads();
#pragma unroll
        for (int L = tid; L < 512; L += 256) {
            int row = L >> 3;
            int kq = L & 7;
            int n = n0 + row;
            float4 v = make_float4(0.f, 0.f, 0.f, 0.f);
            if (n < N_NODES)
                v = *reinterpret_cast<const float4*>(&X[(size_t)n * K + k0 + kq * 4]);
            xs[kq * 4 + 0][row] = v.x;
            xs[kq * 4 + 1][row] = v.y;
            xs[kq * 4 + 2][row] = v.z;
            xs[kq * 4 + 3][row] = v.w;
        }
        __syncthreads();
#pragma unroll 8
        for (int k = 0; k < 32; ++k) {
            const float4 w = *reinterpret_cast<const float4*>(&W[(size_t)(k0 + k) * HC + c0]);
            const float4 xa = *reinterpret_cast<const float4*>(&xs[k][r0]);
            const float4 xb = *reinterpret_cast<const float4*>(&xs[k][r0 + 4]);
            acc[0][0] = fmaf(xa.x, w.x, acc[0][0]);
            acc[0][1] = fmaf(xa.x, w.y, acc[0][1]);
            acc[0][2] = fmaf(xa.x, w.z, acc[0][2]);
            acc[0][3] = fmaf(xa.x, w.w, acc[0][3]);
            acc[1][0] = fmaf(xa.y, w.x, acc[1][0]);
            acc[1][1] = fmaf(xa.y, w.y, acc[1][1]);
            acc[1][2] = fmaf(xa.y, w.z, acc[1][2]);
            acc[1][3] = fmaf(xa.y, w.w, acc[1][3]);
            acc[2][0] = fmaf(xa.z, w.x, acc[2][0]);
            acc[2][1] = fmaf(xa.z, w.y, acc[2][1]);
            acc[2][2] = fmaf(xa.z, w.z, acc[2][2]);
            acc[2][3] = fmaf(xa.z, w.w, acc[2][3]);
            acc[3][0] = fmaf(xa.w, w.x, acc[3][0]);
            acc[3][1] = fmaf(xa.w, w.y, acc[3][1]);
            acc[3][2] = fmaf(xa.w, w.z, acc[3][2]);
            acc[3][3] = fmaf(xa.w, w.w, acc[3][3]);
            acc[4][0] = fmaf(xb.x, w.x, acc[4][0]);
            acc[4][1] = fmaf(xb.x, w.y, acc[4][1]);
            acc[4][2] = fmaf(xb.x, w.z, acc[4][2]);
            acc[4][3] = fmaf(xb.x, w.w, acc[4][3]);
            acc[5][0] = fmaf(xb.y, w.x, acc[5][0]);
            acc[5][1] = fmaf(xb.y, w.y, acc[5][1]);
            acc[5][2] = fmaf(xb.y, w.z, acc[5][2]);
            acc[5][3] = fmaf(xb.y, w.w, acc[5][3]);
            acc[6][0] = fmaf(xb.z, w.x, acc[6][0]);
            acc[6][1] = fmaf(xb.z, w.y, acc[6][1]);
            acc[6][2] = fmaf(xb.z, w.z, acc[6][2]);
            acc[6][3] = fmaf(xb.z, w.w, acc[6][3]);
            acc[7][0] = fmaf(xb.w, w.x, acc[7][0]);
            acc[7][1] = fmaf(xb.w, w.y, acc[7][1]);
            acc[7][2] = fmaf(xb.w, w.z, acc[7][2]);
            acc[7][3] = fmaf(xb.w, w.w, acc[7][3]);
        }
    }
#pragma unroll
    for (int i = 0; i < 8; ++i) {
        int n = n0 + r0 + i;
        if (n < N_NODES)
            *reinterpret_cast<float4*>(&Hout[(size_t)n * HC + c0]) =
                make_float4(acc[i][0], acc[i][1], acc[i][2], acc[i][3]);
    }
}

// ---- per-node attention logits: as/ad [N, H] ----
__global__ void alpha_kernel(const float* __restrict__ Hb,
                             const float* __restrict__ a_src,
                             const float* __restrict__ a_dst,
                             float* __restrict__ as, float* __restrict__ ad) {
    int i = blockIdx.x * blockDim.x + threadIdx.x;  // n*H + h
    if (i >= N_NODES * H_HEADS) return;
    int h = i & 3;
    const float* hp = Hb + (size_t)(i >> 2) * HC + h * C_CH;
    float ssum = 0.f, dsum = 0.f;
#pragma unroll
    for (int c = 0; c < C_CH; ++c) {
        float v = hp[c];
        ssum += v * a_src[h * C_CH + c];
        dsum += v * a_dst[h * C_CH + c];
    }
    as[i] = ssum;
    ad[i] = dsum;
}

// ================= CSR build (once per call) =================
__global__ void count_deg_kernel(const int* __restrict__ ei, int* __restrict__ deg) {
    int e = blockIdx.x * blockDim.x + threadIdx.x;
    if (e >= ETOT) return;
    int d = (e < E_EDGES) ? ei[E_EDGES + e] : (e - E_EDGES);
    atomicAdd(&deg[d], 1);
}

__global__ __launch_bounds__(256) void scan_block_kernel(const int* __restrict__ deg,
                                                         int* __restrict__ excl,
                                                         int* __restrict__ bsum) {
    __shared__ int tmp[256];
    int i = blockIdx.x * 256 + threadIdx.x;
    int v = (i < N_NODES) ? deg[i] : 0;
    tmp[threadIdx.x] = v;
    __syncthreads();
    for (int off = 1; off < 256; off <<= 1) {
        int t = (threadIdx.x >= off) ? tmp[threadIdx.x - off] : 0;
        __syncthreads();
        tmp[threadIdx.x] += t;
        __syncthreads();
    }
    if (i < N_NODES) excl[i] = tmp[threadIdx.x] - v;
    if (threadIdx.x == 255) bsum[blockIdx.x] = tmp[255];
}

__global__ __launch_bounds__(256) void scan_tops_kernel(int* __restrict__ bsum) {
    __shared__ int tmp[256];
    int t = threadIdx.x;
    int v = (t < SCAN_BLOCKS) ? bsum[t] : 0;
    tmp[t] = v;
    __syncthreads();
    for (int off = 1; off < 256; off <<= 1) {
        int u = (t >= off) ? tmp[t - off] : 0;
        __syncthreads();
        tmp[t] += u;
        __syncthreads();
    }
    if (t < SCAN_BLOCKS) bsum[t] = tmp[t] - v;
}

__global__ void scan_add_kernel(int* __restrict__ excl, const int* __restrict__ bsum,
                                int* __restrict__ cursor) {
    int i = blockIdx.x * blockDim.x + threadIdx.x;
    if (i >= N_NODES) return;
    int s = excl[i] + bsum[i >> 8];
    excl[i] = s;     // row_start
    cursor[i] = s;   // scatter cursor
}

__global__ void scatter_edges_kernel(const int* __restrict__ ei,
                                     int* __restrict__ cursor,
                                     int* __restrict__ elist) {
    int e = blockIdx.x * blockDim.x + threadIdx.x;
    if (e >= ETOT) return;
    int s, d;
    if (e < E_EDGES) { s = ei[e]; d = ei[E_EDGES + e]; }
    else             { s = d = e - E_EDGES; }
    int pos = atomicAdd(&cursor[d], 1);
    elist[pos] = s;
}

// ============ fused gather GAT: chunked flash-style softmax + aggregate ============
// 128 threads/node. Parallel phase: thread t computes ev for (head t>>5, edge t&31)
// of a 32-edge chunk; shfl max/sum reduce within head groups; one rescale per chunk.
// Gather phase: serial over chunk edges, p broadcast from LDS, 1 fma per lane.
__global__ __launch_bounds__(128) void gat_gather_kernel(const int* __restrict__ row_start,
                                                         const int* __restrict__ deg,
                                                         const int* __restrict__ elist,
                                                         const float* __restrict__ as,
                                                         const float* __restrict__ ad,
                                                         const float* __restrict__ Hb,
                                                         const float* __restrict__ bias,
                                                         float* __restrict__ out) {
    const int n = blockIdx.x;
    const int t = threadIdx.x;
    const int c = t;            // channel (gather phase)
    const int hg = t >> 5;      // head (both phases: c>>5 == t>>5)
    const int j32 = t & 31;     // edge-in-chunk (softmax phase)
    const int row = row_start[n];
    const int len = deg[n];
    const float ad_n = ad[n * 4 + hg];

    __shared__ int   sbuf[32];
    __shared__ float pbuf[4][32];

    float m = -INFINITY, z = 0.f, acc = 0.f;

    for (int base = 0; base < len; base += 32) {
        const int cl = min(32, len - base);
        if (t < cl) sbuf[t] = elist[row + base + t];
        __syncthreads();

        // ---- parallel softmax phase: 128 edge-head logits at once ----
        float ev = -INFINITY;
        if (j32 < cl) {
            int s = sbuf[j32];
            ev = as[s * 4 + hg] + ad_n;
            ev = ev > 0.f ? ev : ev * NEG_SLOPE;
        }
        // chunk max within the 32-lane head group
        float cm = ev;
#pragma unroll
        for (int off = 16; off > 0; off >>= 1)
            cm = fmaxf(cm, __shfl_xor(cm, off, 32));
        float mnew = fmaxf(m, cm);
        float scale = __expf(m - mnew);   // first chunk: exp(-inf)=0
        z *= scale;
        acc *= scale;
        m = mnew;
        float p = (j32 < cl) ? __expf(ev - m) : 0.f;
        float ps = p;
#pragma unroll
        for (int off = 16; off > 0; off >>= 1)
            ps += __shfl_xor(ps, off, 32);
        z += ps;
        pbuf[hg][j32] = p;
        __syncthreads();

        // ---- gather phase: 1 fma per edge per lane ----
        for (int j = 0; j < cl; ++j) {
            int s = sbuf[j];
            acc = fmaf(pbuf[hg][j], Hb[(size_t)s * HC + c], acc);
        }
        __syncthreads();
    }
    float v = acc / z + bias[c];
    out[(size_t)n * HC + c] = v > 0.f ? v : 0.f;
}

// ---- graph boundaries via binary search on sorted batch ----
__global__ void boundary_kernel(const int* __restrict__ batch,
                                int* __restrict__ gstart,
                                float* __restrict__ cntf) {
    int g = threadIdx.x;
    if (g <= NUM_GRAPHS) {
        int lo = 0, hi = N_NODES;
        while (lo < hi) {
            int mid = (lo + hi) >> 1;
            if (batch[mid] < g) lo = mid + 1; else hi = mid;
        }
        gstart[g] = lo;
    }
    __syncthreads();
    if (g < NUM_GRAPHS) cntf[g] = (float)(gstart[g + 1] - gstart[g]);
}

// ---- pool: 8 blocks per graph, register accumulation, 1 atomic per thread ----
__global__ __launch_bounds__(128) void pool_seg_kernel(const float* __restrict__ out,
                                                       const int* __restrict__ gstart,
                                                       float* __restrict__ sums) {
    const int g = blockIdx.x >> 3;
    const int split = blockIdx.x & 7;
    const int c = threadIdx.x;
    const int start = gstart[g], end = gstart[g + 1];
    const int len = end - start;
    const int chunk = (len + POOL_SPLIT - 1) / POOL_SPLIT;
    const int s0 = start + split * chunk;
    const int s1 = min(s0 + chunk, end);
    float acc = 0.f;
    for (int n = s0; n < s1; ++n) acc += out[(size_t)n * HC + c];
    if (s0 < s1) atomicAdd(&sums[g * HC + c], acc);
}

// ---- classifier ----
__global__ void classifier_kernel(const float* __restrict__ sums,
                                  const float* __restrict__ cnt,
                                  const float* __restrict__ Wc1,
                                  const float* __restrict__ bc1,
                                  const float* __restrict__ Wc2,
                                  const float* __restrict__ bc2,
                                  float* __restrict__ outp) {
    int g = threadIdx.x;
    if (g >= NUM_GRAPHS) return;
    float inv = 1.0f / cnt[g];
    float hidden[C_CH];
#pragma unroll 4
    for (int j = 0; j < C_CH; ++j) {
        float acc = bc1[j];
        for (int c = 0; c < HC; ++c)
            acc += (sums[g * HC + c] * inv) * Wc1[c * C_CH + j];
        hidden[j] = acc;
    }
    for (int k = 0; k < NUM_CLASSES; ++k) {
        float acc = bc2[k];
#pragma unroll
        for (int j = 0; j < C_CH; ++j) acc += hidden[j] * Wc2[j * NUM_CLASSES + k];
        outp[g * NUM_CLASSES + k] = 1.0f / (1.0f + __expf(-acc));
    }
}

extern "C" void kernel_launch(void* const* d_in, const int* in_sizes, int n_in,
                              void* d_out, int out_size, void* d_ws, size_t ws_size,
                              hipStream_t stream) {
    const float* x   = (const float*)d_in[0];
    const int*   ei  = (const int*)  d_in[1];
    const int*   bat = (const int*)  d_in[2];
    const float* W1  = (const float*)d_in[3];
    const float* as1 = (const float*)d_in[4];
    const float* ad1 = (const float*)d_in[5];
    const float* b1  = (const float*)d_in[6];
    const float* W2  = (const float*)d_in[7];
    const float* as2 = (const float*)d_in[8];
    const float* ad2 = (const float*)d_in[9];
    const float* b2  = (const float*)d_in[10];
    const float* Wc1 = (const float*)d_in[11];
    const float* bc1 = (const float*)d_in[12];
    const float* Wc2 = (const float*)d_in[13];
    const float* bc2 = (const float*)d_in[14];
    float* outp = (float*)d_out;

    char* ws = (char*)d_ws;
    float* hbuf = (float*)ws;  ws += (size_t)N_NODES * HC * 4;
    float* obuf = (float*)ws;  ws += (size_t)N_NODES * HC * 4;
    float* asb  = (float*)ws;  ws += (size_t)N_NODES * H_HEADS * 4;
    float* adb  = (float*)ws;  ws += (size_t)N_NODES * H_HEADS * 4;
    int* elist    = (int*)ws;  ws += (size_t)ETOT * 4;
    int* row_start= (int*)ws;  ws += (size_t)N_NODES * 4;
    int* degb     = (int*)ws;  ws += (size_t)N_NODES * 4;
    int* cursor   = (int*)ws;  ws += (size_t)N_NODES * 4;
    int* bsum     = (int*)ws;  ws += 256 * 4;
    int* gstart   = (int*)ws;  ws += (NUM_GRAPHS + 1) * 4;
    float* sums = (float*)ws;  ws += (size_t)NUM_GRAPHS * HC * 4;
    float* cnt  = (float*)ws;  ws += (size_t)NUM_GRAPHS * 4;

    const int nh_blocks  = (N_NODES * H_HEADS + 255) / 256;
    const int n_blocks   = (N_NODES + 255) / 256;
    const int e_blocks   = (ETOT + 255) / 256;
    const int gemm_blocks = (N_NODES + 63) / 64;

    // ---------------- CSR build (shared by both layers) ----------------
    hipMemsetAsync(degb, 0, (size_t)N_NODES * 4, stream);
    count_deg_kernel<<<e_blocks, 256, 0, stream>>>(ei, degb);
    scan_block_kernel<<<SCAN_BLOCKS, 256, 0, stream>>>(degb, row_start, bsum);
    scan_tops_kernel<<<1, 256, 0, stream>>>(bsum);
    scan_add_kernel<<<n_blocks, 256, 0, stream>>>(row_start, bsum, cursor);
    scatter_edges_kernel<<<e_blocks, 256, 0, stream>>>(ei, cursor, elist);

    // ---------------- layer 1 ----------------
    gemm_rb<F_IN_DIM><<<gemm_blocks, 256, 0, stream>>>(x, W1, hbuf);
    alpha_kernel<<<nh_blocks, 256, 0, stream>>>(hbuf, as1, ad1, asb, adb);
    gat_gather_kernel<<<N_NODES, 128, 0, stream>>>(row_start, degb, elist,
                                                   asb, adb, hbuf, b1, obuf);

    // ---------------- layer 2 ----------------
    gemm_rb<HC><<<gemm_blocks, 256, 0, stream>>>(obuf, W2, hbuf);
    alpha_kernel<<<nh_blocks, 256, 0, stream>>>(hbuf, as2, ad2, asb, adb);
    gat_gather_kernel<<<N_NODES, 128, 0, stream>>>(row_start, degb, elist,
                                                   asb, adb, hbuf, b2, obuf);

    // ---------------- pool + classifier ----------------
    boundary_kernel<<<1, 128, 0, stream>>>(bat, gstart, cnt);
    hipMemsetAsync(sums, 0, (size_t)NUM_GRAPHS * HC * 4, stream);
    pool_seg_kernel<<<NUM_GRAPHS * POOL_SPLIT, 128, 0, stream>>>(obuf, gstart, sums);
    classifier_kernel<<<1, 64, 0, stream>>>(sums, cnt, Wc1, bc1, Wc2, bc2, outp);
}

// Round 9
// 711.431 us; speedup vs baseline: 4.0011x; 1.0998x over previous
//
#include <hip/hip_runtime.h>
#include <math.h>

#define N_NODES 50000
#define E_EDGES 1600000
#define F_IN_DIM 256
#define H_HEADS 4
#define C_CH 32
#define HC 128
#define NUM_CLASSES 16
#define NUM_GRAPHS 64
#define ETOT (E_EDGES + N_NODES)
#define NEG_SLOPE 0.2f
#define SCAN_BLOCKS ((N_NODES + 255) / 256)   // 196
#define NBUCK ((N_NODES + 255) / 256)         // 196 coarse buckets (256 nodes each)
#define SCAT_BLOCKS 512
#define POOL_SPLIT 8

// ---- register-blocked GEMM: Hout[n, 0:128] = X[n, 0:K] @ W[K, 128] ----
template <int K>
__global__ __launch_bounds__(256) void gemm_rb(const float* __restrict__ X,
                                               const float* __restrict__ W,
                                               float* __restrict__ Hout) {
    __shared__ float xs[32][68];
    const int n0 = blockIdx.x * 64;
    const int tid = threadIdx.x;
    const int rg = tid >> 5;
    const int cg = tid & 31;
    const int r0 = rg * 8;
    const int c0 = cg * 4;
    float acc[8][4];
#pragma unroll
    for (int i = 0; i < 8; ++i)
#pragma unroll
        for (int j = 0; j < 4; ++j) acc[i][j] = 0.f;

    for (int k0 = 0; k0 < K; k0 += 32) {
        __syncthreads();
#pragma unroll
        for (int L = tid; L < 512; L += 256) {
            int row = L >> 3;
            int kq = L & 7;
            int n = n0 + row;
            float4 v = make_float4(0.f, 0.f, 0.f, 0.f);
            if (n < N_NODES)
                v = *reinterpret_cast<const float4*>(&X[(size_t)n * K + k0 + kq * 4]);
            xs[kq * 4 + 0][row] = v.x;
            xs[kq * 4 + 1][row] = v.y;
            xs[kq * 4 + 2][row] = v.z;
            xs[kq * 4 + 3][row] = v.w;
        }
        __syncthreads();
#pragma unroll 8
        for (int k = 0; k < 32; ++k) {
            const float4 w = *reinterpret_cast<const float4*>(&W[(size_t)(k0 + k) * HC + c0]);
            const float4 xa = *reinterpret_cast<const float4*>(&xs[k][r0]);
            const float4 xb = *reinterpret_cast<const float4*>(&xs[k][r0 + 4]);
            acc[0][0] = fmaf(xa.x, w.x, acc[0][0]);
            acc[0][1] = fmaf(xa.x, w.y, acc[0][1]);
            acc[0][2] = fmaf(xa.x, w.z, acc[0][2]);
            acc[0][3] = fmaf(xa.x, w.w, acc[0][3]);
            acc[1][0] = fmaf(xa.y, w.x, acc[1][0]);
            acc[1][1] = fmaf(xa.y, w.y, acc[1][1]);
            acc[1][2] = fmaf(xa.y, w.z, acc[1][2]);
            acc[1][3] = fmaf(xa.y, w.w, acc[1][3]);
            acc[2][0] = fmaf(xa.z, w.x, acc[2][0]);
            acc[2][1] = fmaf(xa.z, w.y, acc[2][1]);
            acc[2][2] = fmaf(xa.z, w.z, acc[2][2]);
            acc[2][3] = fmaf(xa.z, w.w, acc[2][3]);
            acc[3][0] = fmaf(xa.w, w.x, acc[3][0]);
            acc[3][1] = fmaf(xa.w, w.y, acc[3][1]);
            acc[3][2] = fmaf(xa.w, w.z, acc[3][2]);
            acc[3][3] = fmaf(xa.w, w.w, acc[3][3]);
            acc[4][0] = fmaf(xb.x, w.x, acc[4][0]);
            acc[4][1] = fmaf(xb.x, w.y, acc[4][1]);
            acc[4][2] = fmaf(xb.x, w.z, acc[4][2]);
            acc[4][3] = fmaf(xb.x, w.w, acc[4][3]);
            acc[5][0] = fmaf(xb.y, w.x, acc[5][0]);
            acc[5][1] = fmaf(xb.y, w.y, acc[5][1]);
            acc[5][2] = fmaf(xb.y, w.z, acc[5][2]);
            acc[5][3] = fmaf(xb.y, w.w, acc[5][3]);
            acc[6][0] = fmaf(xb.z, w.x, acc[6][0]);
            acc[6][1] = fmaf(xb.z, w.y, acc[6][1]);
            acc[6][2] = fmaf(xb.z, w.z, acc[6][2]);
            acc[6][3] = fmaf(xb.z, w.w, acc[6][3]);
            acc[7][0] = fmaf(xb.w, w.x, acc[7][0]);
            acc[7][1] = fmaf(xb.w, w.y, acc[7][1]);
            acc[7][2] = fmaf(xb.w, w.z, acc[7][2]);
            acc[7][3] = fmaf(xb.w, w.w, acc[7][3]);
        }
    }
#pragma unroll
    for (int i = 0; i < 8; ++i) {
        int n = n0 + r0 + i;
        if (n < N_NODES)
            *reinterpret_cast<float4*>(&Hout[(size_t)n * HC + c0]) =
                make_float4(acc[i][0], acc[i][1], acc[i][2], acc[i][3]);
    }
}

// ---- per-node attention logits: as/ad [N, H] ----
__global__ void alpha_kernel(const float* __restrict__ Hb,
                             const float* __restrict__ a_src,
                             const float* __restrict__ a_dst,
                             float* __restrict__ as, float* __restrict__ ad) {
    int i = blockIdx.x * blockDim.x + threadIdx.x;  // n*H + h
    if (i >= N_NODES * H_HEADS) return;
    int h = i & 3;
    const float* hp = Hb + (size_t)(i >> 2) * HC + h * C_CH;
    float ssum = 0.f, dsum = 0.f;
#pragma unroll
    for (int c = 0; c < C_CH; ++c) {
        float v = hp[c];
        ssum += v * a_src[h * C_CH + c];
        dsum += v * a_dst[h * C_CH + c];
    }
    as[i] = ssum;
    ad[i] = dsum;
}

// ================= CSR build (once per call) =================
__global__ void count_deg_kernel(const int* __restrict__ ei, int* __restrict__ deg) {
    int e = blockIdx.x * blockDim.x + threadIdx.x;
    if (e >= ETOT) return;
    int d = (e < E_EDGES) ? ei[E_EDGES + e] : (e - E_EDGES);
    atomicAdd(&deg[d], 1);
}

__global__ __launch_bounds__(256) void scan_block_kernel(const int* __restrict__ deg,
                                                         int* __restrict__ excl,
                                                         int* __restrict__ bsum) {
    __shared__ int tmp[256];
    int i = blockIdx.x * 256 + threadIdx.x;
    int v = (i < N_NODES) ? deg[i] : 0;
    tmp[threadIdx.x] = v;
    __syncthreads();
    for (int off = 1; off < 256; off <<= 1) {
        int t = (threadIdx.x >= off) ? tmp[threadIdx.x - off] : 0;
        __syncthreads();
        tmp[threadIdx.x] += t;
        __syncthreads();
    }
    if (i < N_NODES) excl[i] = tmp[threadIdx.x] - v;
    if (threadIdx.x == 255) bsum[blockIdx.x] = tmp[255];
}

__global__ __launch_bounds__(256) void scan_tops_kernel(int* __restrict__ bsum) {
    __shared__ int tmp[256];
    int t = threadIdx.x;
    int v = (t < SCAN_BLOCKS) ? bsum[t] : 0;
    tmp[t] = v;
    __syncthreads();
    for (int off = 1; off < 256; off <<= 1) {
        int u = (t >= off) ? tmp[t - off] : 0;
        __syncthreads();
        tmp[t] += u;
        __syncthreads();
    }
    if (t < SCAN_BLOCKS) bsum[t] = tmp[t] - v;
}

// finalize row_start; seed per-bucket cursors for the coarse scatter
__global__ void scan_add_kernel(int* __restrict__ excl, const int* __restrict__ bsum,
                                int* __restrict__ bcursor) {
    int i = blockIdx.x * blockDim.x + threadIdx.x;
    if (i >= N_NODES) return;
    int s = excl[i] + bsum[i >> 8];
    excl[i] = s;                         // row_start
    if ((i & 255) == 0) bcursor[i >> 8] = s;  // bucket base = row_start[b*256]
}

// ---- coarse scatter: bin packed edges (d<65536, s<65536 -> one u32) by d>>8 ----
// per-block LDS histogram -> one global reservation atomic per (block,bucket),
// then grouped writes: runs of consecutive u32 per bucket per block.
__global__ __launch_bounds__(256) void bucket_scatter_kernel(const int* __restrict__ ei,
                                                             int* __restrict__ bcursor,
                                                             unsigned* __restrict__ bucket_buf) {
    __shared__ int hist[NBUCK];
    __shared__ int base[NBUCK];
    const int tid = threadIdx.x;
    const int chunk = (ETOT + SCAT_BLOCKS - 1) / SCAT_BLOCKS;
    const int e0 = blockIdx.x * chunk;
    const int e1 = min(e0 + chunk, ETOT);
    for (int i = tid; i < NBUCK; i += 256) hist[i] = 0;
    __syncthreads();
    for (int e = e0 + tid; e < e1; e += 256) {
        int d = (e < E_EDGES) ? ei[E_EDGES + e] : (e - E_EDGES);
        atomicAdd(&hist[d >> 8], 1);
    }
    __syncthreads();
    for (int i = tid; i < NBUCK; i += 256) {
        int cnt = hist[i];
        base[i] = (cnt > 0) ? atomicAdd(&bcursor[i], cnt) : 0;
        hist[i] = 0;  // reuse as local cursor
    }
    __syncthreads();
    for (int e = e0 + tid; e < e1; e += 256) {
        int s, d;
        if (e < E_EDGES) { s = ei[e]; d = ei[E_EDGES + e]; }
        else             { s = d = e - E_EDGES; }
        int b = d >> 8;
        int pos = base[b] + atomicAdd(&hist[b], 1);
        bucket_buf[pos] = ((unsigned)d << 16) | (unsigned)s;
    }
}

// ---- fine scatter: one block per bucket, LDS cursors, private contiguous window ----
__global__ __launch_bounds__(256) void bucket_sort_kernel(const unsigned* __restrict__ bucket_buf,
                                                          const int* __restrict__ row_start,
                                                          int* __restrict__ elist) {
    __shared__ int cur[256];
    const int b = blockIdx.x;
    const int n0 = b * 256;
    const int tid = threadIdx.x;
    if (n0 + tid < N_NODES) cur[tid] = row_start[n0 + tid];
    const int start = row_start[n0];
    const int end = (b == NBUCK - 1) ? ETOT : row_start[n0 + 256];
    __syncthreads();
    for (int j = start + tid; j < end; j += 256) {
        unsigned p = bucket_buf[j];
        int d = (int)(p >> 16);
        int s = (int)(p & 0xffffu);
        int pos = atomicAdd(&cur[d - n0], 1);
        elist[pos] = s;
    }
}

// ============ fused gather GAT: chunked flash-style softmax + aggregate ============
__global__ __launch_bounds__(128) void gat_gather_kernel(const int* __restrict__ row_start,
                                                         const int* __restrict__ deg,
                                                         const int* __restrict__ elist,
                                                         const float* __restrict__ as,
                                                         const float* __restrict__ ad,
                                                         const float* __restrict__ Hb,
                                                         const float* __restrict__ bias,
                                                         float* __restrict__ out) {
    const int n = blockIdx.x;
    const int t = threadIdx.x;
    const int c = t;            // channel (gather phase)
    const int hg = t >> 5;      // head
    const int j32 = t & 31;     // edge-in-chunk (softmax phase)
    const int row = row_start[n];
    const int len = deg[n];
    const float ad_n = ad[n * 4 + hg];

    __shared__ int   sbuf[32];
    __shared__ float pbuf[4][32];

    float m = -INFINITY, z = 0.f, acc = 0.f;

    for (int base = 0; base < len; base += 32) {
        const int cl = min(32, len - base);
        if (t < cl) sbuf[t] = elist[row + base + t];
        __syncthreads();

        float ev = -INFINITY;
        if (j32 < cl) {
            int s = sbuf[j32];
            ev = as[s * 4 + hg] + ad_n;
            ev = ev > 0.f ? ev : ev * NEG_SLOPE;
        }
        float cm = ev;
#pragma unroll
        for (int off = 16; off > 0; off >>= 1)
            cm = fmaxf(cm, __shfl_xor(cm, off, 32));
        float mnew = fmaxf(m, cm);
        float scale = __expf(m - mnew);
        z *= scale;
        acc *= scale;
        m = mnew;
        float p = (j32 < cl) ? __expf(ev - m) : 0.f;
        float ps = p;
#pragma unroll
        for (int off = 16; off > 0; off >>= 1)
            ps += __shfl_xor(ps, off, 32);
        z += ps;
        pbuf[hg][j32] = p;
        __syncthreads();

        for (int j = 0; j < cl; ++j) {
            int s = sbuf[j];
            acc = fmaf(pbuf[hg][j], Hb[(size_t)s * HC + c], acc);
        }
        __syncthreads();
    }
    float v = acc / z + bias[c];
    out[(size_t)n * HC + c] = v > 0.f ? v : 0.f;
}

// ---- graph boundaries via binary search on sorted batch ----
__global__ void boundary_kernel(const int* __restrict__ batch,
                                int* __restrict__ gstart,
                                float* __restrict__ cntf) {
    int g = threadIdx.x;
    if (g <= NUM_GRAPHS) {
        int lo = 0, hi = N_NODES;
        while (lo < hi) {
            int mid = (lo + hi) >> 1;
            if (batch[mid] < g) lo = mid + 1; else hi = mid;
        }
        gstart[g] = lo;
    }
    __syncthreads();
    if (g < NUM_GRAPHS) cntf[g] = (float)(gstart[g + 1] - gstart[g]);
}

// ---- pool: 8 blocks per graph, register accumulation, 1 atomic per thread ----
__global__ __launch_bounds__(128) void pool_seg_kernel(const float* __restrict__ out,
                                                       const int* __restrict__ gstart,
                                                       float* __restrict__ sums) {
    const int g = blockIdx.x >> 3;
    const int split = blockIdx.x & 7;
    const int c = threadIdx.x;
    const int start = gstart[g], end = gstart[g + 1];
    const int len = end - start;
    const int chunk = (len + POOL_SPLIT - 1) / POOL_SPLIT;
    const int s0 = start + split * chunk;
    const int s1 = min(s0 + chunk, end);
    float acc = 0.f;
    for (int n = s0; n < s1; ++n) acc += out[(size_t)n * HC + c];
    if (s0 < s1) atomicAdd(&sums[g * HC + c], acc);
}

// ---- classifier ----
__global__ void classifier_kernel(const float* __restrict__ sums,
                                  const float* __restrict__ cnt,
                                  const float* __restrict__ Wc1,
                                  const float* __restrict__ bc1,
                                  const float* __restrict__ Wc2,
                                  const float* __restrict__ bc2,
                                  float* __restrict__ outp) {
    int g = threadIdx.x;
    if (g >= NUM_GRAPHS) return;
    float inv = 1.0f / cnt[g];
    float hidden[C_CH];
#pragma unroll 4
    for (int j = 0; j < C_CH; ++j) {
        float acc = bc1[j];
        for (int c = 0; c < HC; ++c)
            acc += (sums[g * HC + c] * inv) * Wc1[c * C_CH + j];
        hidden[j] = acc;
    }
    for (int k = 0; k < NUM_CLASSES; ++k) {
        float acc = bc2[k];
#pragma unroll
        for (int j = 0; j < C_CH; ++j) acc += hidden[j] * Wc2[j * NUM_CLASSES + k];
        outp[g * NUM_CLASSES + k] = 1.0f / (1.0f + __expf(-acc));
    }
}

extern "C" void kernel_launch(void* const* d_in, const int* in_sizes, int n_in,
                              void* d_out, int out_size, void* d_ws, size_t ws_size,
                              hipStream_t stream) {
    const float* x   = (const float*)d_in[0];
    const int*   ei  = (const int*)  d_in[1];
    const int*   bat = (const int*)  d_in[2];
    const float* W1  = (const float*)d_in[3];
    const float* as1 = (const float*)d_in[4];
    const float* ad1 = (const float*)d_in[5];
    const float* b1  = (const float*)d_in[6];
    const float* W2  = (const float*)d_in[7];
    const float* as2 = (const float*)d_in[8];
    const float* ad2 = (const float*)d_in[9];
    const float* b2  = (const float*)d_in[10];
    const float* Wc1 = (const float*)d_in[11];
    const float* bc1 = (const float*)d_in[12];
    const float* Wc2 = (const float*)d_in[13];
    const float* bc2 = (const float*)d_in[14];
    float* outp = (float*)d_out;

    char* ws = (char*)d_ws;
    float* hbuf = (float*)ws;  ws += (size_t)N_NODES * HC * 4;
    float* obuf = (float*)ws;  ws += (size_t)N_NODES * HC * 4;
    float* asb  = (float*)ws;  ws += (size_t)N_NODES * H_HEADS * 4;
    float* adb  = (float*)ws;  ws += (size_t)N_NODES * H_HEADS * 4;
    int* elist    = (int*)ws;  ws += (size_t)ETOT * 4;
    unsigned* bucket_buf = (unsigned*)ws; ws += (size_t)ETOT * 4;
    int* row_start= (int*)ws;  ws += (size_t)N_NODES * 4;
    int* degb     = (int*)ws;  ws += (size_t)N_NODES * 4;
    int* bcursor  = (int*)ws;  ws += (size_t)NBUCK * 4;
    int* bsum     = (int*)ws;  ws += 256 * 4;
    int* gstart   = (int*)ws;  ws += (NUM_GRAPHS + 1) * 4;
    float* sums = (float*)ws;  ws += (size_t)NUM_GRAPHS * HC * 4;
    float* cnt  = (float*)ws;  ws += (size_t)NUM_GRAPHS * 4;

    const int nh_blocks  = (N_NODES * H_HEADS + 255) / 256;
    const int n_blocks   = (N_NODES + 255) / 256;
    const int e_blocks   = (ETOT + 255) / 256;
    const int gemm_blocks = (N_NODES + 63) / 64;

    // ---------------- CSR build (shared by both layers) ----------------
    hipMemsetAsync(degb, 0, (size_t)N_NODES * 4, stream);
    count_deg_kernel<<<e_blocks, 256, 0, stream>>>(ei, degb);
    scan_block_kernel<<<SCAN_BLOCKS, 256, 0, stream>>>(degb, row_start, bsum);
    scan_tops_kernel<<<1, 256, 0, stream>>>(bsum);
    scan_add_kernel<<<n_blocks, 256, 0, stream>>>(row_start, bsum, bcursor);
    bucket_scatter_kernel<<<SCAT_BLOCKS, 256, 0, stream>>>(ei, bcursor, bucket_buf);
    bucket_sort_kernel<<<NBUCK, 256, 0, stream>>>(bucket_buf, row_start, elist);

    // ---------------- layer 1 ----------------
    gemm_rb<F_IN_DIM><<<gemm_blocks, 256, 0, stream>>>(x, W1, hbuf);
    alpha_kernel<<<nh_blocks, 256, 0, stream>>>(hbuf, as1, ad1, asb, adb);
    gat_gather_kernel<<<N_NODES, 128, 0, stream>>>(row_start, degb, elist,
                                                   asb, adb, hbuf, b1, obuf);

    // ---------------- layer 2 ----------------
    gemm_rb<HC><<<gemm_blocks, 256, 0, stream>>>(obuf, W2, hbuf);
    alpha_kernel<<<nh_blocks, 256, 0, stream>>>(hbuf, as2, ad2, asb, adb);
    gat_gather_kernel<<<N_NODES, 128, 0, stream>>>(row_start, degb, elist,
                                                   asb, adb, hbuf, b2, obuf);

    // ---------------- pool + classifier ----------------
    boundary_kernel<<<1, 128, 0, stream>>>(bat, gstart, cnt);
    hipMemsetAsync(sums, 0, (size_t)NUM_GRAPHS * HC * 4, stream);
    pool_seg_kernel<<<NUM_GRAPHS * POOL_SPLIT, 128, 0, stream>>>(obuf, gstart, sums);
    classifier_kernel<<<1, 64, 0, stream>>>(sums, cnt, Wc1, bc1, Wc2, bc2, outp);
}

// Round 11
// 637.901 us; speedup vs baseline: 4.4623x; 1.1153x over previous
//
#include <hip/hip_runtime.h>
#include <math.h>

#define N_NODES 50000
#define E_EDGES 1600000
#define F_IN_DIM 256
#define H_HEADS 4
#define C_CH 32
#define HC 128
#define NUM_CLASSES 16
#define NUM_GRAPHS 64
#define ETOT (E_EDGES + N_NODES)
#define NEG_SLOPE 0.2f
#define SCAN_BLOCKS ((N_NODES + 255) / 256)   // 196
#define NBUCK ((N_NODES + 255) / 256)         // 196 coarse buckets (256 nodes each)
#define SCAT_BLOCKS 512
#define POOL_SPLIT 8

// float -> bf16 (round-to-nearest-even)
__device__ __forceinline__ unsigned short f2bf(float f) {
    unsigned u = __float_as_uint(f);
    return (unsigned short)((u + 0x7FFFu + ((u >> 16) & 1u)) >> 16);
}

// ---- register-blocked GEMM: Hout[n,0:128] = X[n,0:K] @ W[K,128]; also bf16 copy ----
template <int K>
__global__ __launch_bounds__(256) void gemm_rb(const float* __restrict__ X,
                                               const float* __restrict__ W,
                                               float* __restrict__ Hout,
                                               unsigned short* __restrict__ H16) {
    __shared__ float xs[32][68];
    const int n0 = blockIdx.x * 64;
    const int tid = threadIdx.x;
    const int rg = tid >> 5;
    const int cg = tid & 31;
    const int r0 = rg * 8;
    const int c0 = cg * 4;
    float acc[8][4];
#pragma unroll
    for (int i = 0; i < 8; ++i)
#pragma unroll
        for (int j = 0; j < 4; ++j) acc[i][j] = 0.f;

    for (int k0 = 0; k0 < K; k0 += 32) {
        __syncthreads();
#pragma unroll
        for (int L = tid; L < 512; L += 256) {
            int row = L >> 3;
            int kq = L & 7;
            int n = n0 + row;
            float4 v = make_float4(0.f, 0.f, 0.f, 0.f);
            if (n < N_NODES)
                v = *reinterpret_cast<const float4*>(&X[(size_t)n * K + k0 + kq * 4]);
            xs[kq * 4 + 0][row] = v.x;
            xs[kq * 4 + 1][row] = v.y;
            xs[kq * 4 + 2][row] = v.z;
            xs[kq * 4 + 3][row] = v.w;
        }
        __syncthreads();
#pragma unroll 8
        for (int k = 0; k < 32; ++k) {
            const float4 w = *reinterpret_cast<const float4*>(&W[(size_t)(k0 + k) * HC + c0]);
            const float4 xa = *reinterpret_cast<const float4*>(&xs[k][r0]);
            const float4 xb = *reinterpret_cast<const float4*>(&xs[k][r0 + 4]);
            acc[0][0] = fmaf(xa.x, w.x, acc[0][0]);
            acc[0][1] = fmaf(xa.x, w.y, acc[0][1]);
            acc[0][2] = fmaf(xa.x, w.z, acc[0][2]);
            acc[0][3] = fmaf(xa.x, w.w, acc[0][3]);
            acc[1][0] = fmaf(xa.y, w.x, acc[1][0]);
            acc[1][1] = fmaf(xa.y, w.y, acc[1][1]);
            acc[1][2] = fmaf(xa.y, w.z, acc[1][2]);
            acc[1][3] = fmaf(xa.y, w.w, acc[1][3]);
            acc[2][0] = fmaf(xa.z, w.x, acc[2][0]);
            acc[2][1] = fmaf(xa.z, w.y, acc[2][1]);
            acc[2][2] = fmaf(xa.z, w.z, acc[2][2]);
            acc[2][3] = fmaf(xa.z, w.w, acc[2][3]);
            acc[3][0] = fmaf(xa.w, w.x, acc[3][0]);
            acc[3][1] = fmaf(xa.w, w.y, acc[3][1]);
            acc[3][2] = fmaf(xa.w, w.z, acc[3][2]);
            acc[3][3] = fmaf(xa.w, w.w, acc[3][3]);
            acc[4][0] = fmaf(xb.x, w.x, acc[4][0]);
            acc[4][1] = fmaf(xb.x, w.y, acc[4][1]);
            acc[4][2] = fmaf(xb.x, w.z, acc[4][2]);
            acc[4][3] = fmaf(xb.x, w.w, acc[4][3]);
            acc[5][0] = fmaf(xb.y, w.x, acc[5][0]);
            acc[5][1] = fmaf(xb.y, w.y, acc[5][1]);
            acc[5][2] = fmaf(xb.y, w.z, acc[5][2]);
            acc[5][3] = fmaf(xb.y, w.w, acc[5][3]);
            acc[6][0] = fmaf(xb.z, w.x, acc[6][0]);
            acc[6][1] = fmaf(xb.z, w.y, acc[6][1]);
            acc[6][2] = fmaf(xb.z, w.z, acc[6][2]);
            acc[6][3] = fmaf(xb.z, w.w, acc[6][3]);
            acc[7][0] = fmaf(xb.w, w.x, acc[7][0]);
            acc[7][1] = fmaf(xb.w, w.y, acc[7][1]);
            acc[7][2] = fmaf(xb.w, w.z, acc[7][2]);
            acc[7][3] = fmaf(xb.w, w.w, acc[7][3]);
        }
    }
#pragma unroll
    for (int i = 0; i < 8; ++i) {
        int n = n0 + r0 + i;
        if (n < N_NODES) {
            *reinterpret_cast<float4*>(&Hout[(size_t)n * HC + c0]) =
                make_float4(acc[i][0], acc[i][1], acc[i][2], acc[i][3]);
            ushort4 b;
            b.x = f2bf(acc[i][0]);
            b.y = f2bf(acc[i][1]);
            b.z = f2bf(acc[i][2]);
            b.w = f2bf(acc[i][3]);
            *reinterpret_cast<ushort4*>(&H16[(size_t)n * HC + c0]) = b;
        }
    }
}

// ---- per-node attention logits: as/ad [N, H] ----
__global__ void alpha_kernel(const float* __restrict__ Hb,
                             const float* __restrict__ a_src,
                             const float* __restrict__ a_dst,
                             float* __restrict__ as, float* __restrict__ ad) {
    int i = blockIdx.x * blockDim.x + threadIdx.x;  // n*H + h
    if (i >= N_NODES * H_HEADS) return;
    int h = i & 3;
    const float* hp = Hb + (size_t)(i >> 2) * HC + h * C_CH;
    float ssum = 0.f, dsum = 0.f;
#pragma unroll
    for (int c = 0; c < C_CH; ++c) {
        float v = hp[c];
        ssum += v * a_src[h * C_CH + c];
        dsum += v * a_dst[h * C_CH + c];
    }
    as[i] = ssum;
    ad[i] = dsum;
}

// ================= CSR build (once per call) =================
__global__ void count_deg_kernel(const int* __restrict__ ei, int* __restrict__ deg) {
    int e = blockIdx.x * blockDim.x + threadIdx.x;
    if (e >= ETOT) return;
    int d = (e < E_EDGES) ? ei[E_EDGES + e] : (e - E_EDGES);
    atomicAdd(&deg[d], 1);
}

__global__ __launch_bounds__(256) void scan_block_kernel(const int* __restrict__ deg,
                                                         int* __restrict__ excl,
                                                         int* __restrict__ bsum) {
    __shared__ int tmp[256];
    int i = blockIdx.x * 256 + threadIdx.x;
    int v = (i < N_NODES) ? deg[i] : 0;
    tmp[threadIdx.x] = v;
    __syncthreads();
    for (int off = 1; off < 256; off <<= 1) {
        int t = (threadIdx.x >= off) ? tmp[threadIdx.x - off] : 0;
        __syncthreads();
        tmp[threadIdx.x] += t;
        __syncthreads();
    }
    if (i < N_NODES) excl[i] = tmp[threadIdx.x] - v;
    if (threadIdx.x == 255) bsum[blockIdx.x] = tmp[255];
}

__global__ __launch_bounds__(256) void scan_tops_kernel(int* __restrict__ bsum) {
    __shared__ int tmp[256];
    int t = threadIdx.x;
    int v = (t < SCAN_BLOCKS) ? bsum[t] : 0;
    tmp[t] = v;
    __syncthreads();
    for (int off = 1; off < 256; off <<= 1) {
        int u = (t >= off) ? tmp[t - off] : 0;
        __syncthreads();
        tmp[t] += u;
        __syncthreads();
    }
    if (t < SCAN_BLOCKS) bsum[t] = tmp[t] - v;
}

// finalize row_start; seed per-bucket cursors for the coarse scatter
__global__ void scan_add_kernel(int* __restrict__ excl, const int* __restrict__ bsum,
                                int* __restrict__ bcursor) {
    int i = blockIdx.x * blockDim.x + threadIdx.x;
    if (i >= N_NODES) return;
    int s = excl[i] + bsum[i >> 8];
    excl[i] = s;                              // row_start
    if ((i & 255) == 0) bcursor[i >> 8] = s;  // bucket base
}

// ---- coarse scatter: bin packed edges (d<<16|s) by d>>8 ----
__global__ __launch_bounds__(256) void bucket_scatter_kernel(const int* __restrict__ ei,
                                                             int* __restrict__ bcursor,
                                                             unsigned* __restrict__ bucket_buf) {
    __shared__ int hist[NBUCK];
    __shared__ int base[NBUCK];
    const int tid = threadIdx.x;
    const int chunk = (ETOT + SCAT_BLOCKS - 1) / SCAT_BLOCKS;
    const int e0 = blockIdx.x * chunk;
    const int e1 = min(e0 + chunk, ETOT);
    for (int i = tid; i < NBUCK; i += 256) hist[i] = 0;
    __syncthreads();
    for (int e = e0 + tid; e < e1; e += 256) {
        int d = (e < E_EDGES) ? ei[E_EDGES + e] : (e - E_EDGES);
        atomicAdd(&hist[d >> 8], 1);
    }
    __syncthreads();
    for (int i = tid; i < NBUCK; i += 256) {
        int cnt = hist[i];
        base[i] = (cnt > 0) ? atomicAdd(&bcursor[i], cnt) : 0;
        hist[i] = 0;  // reuse as local cursor
    }
    __syncthreads();
    for (int e = e0 + tid; e < e1; e += 256) {
        int s, d;
        if (e < E_EDGES) { s = ei[e]; d = ei[E_EDGES + e]; }
        else             { s = d = e - E_EDGES; }
        int b = d >> 8;
        int pos = base[b] + atomicAdd(&hist[b], 1);
        bucket_buf[pos] = ((unsigned)d << 16) | (unsigned)s;
    }
}

// ---- fine scatter: one block per bucket, LDS cursors, private window ----
__global__ __launch_bounds__(256) void bucket_sort_kernel(const unsigned* __restrict__ bucket_buf,
                                                          const int* __restrict__ row_start,
                                                          int* __restrict__ elist) {
    __shared__ int cur[256];
    const int b = blockIdx.x;
    const int n0 = b * 256;
    const int tid = threadIdx.x;
    if (n0 + tid < N_NODES) cur[tid] = row_start[n0 + tid];
    const int start = row_start[n0];
    const int end = (b == NBUCK - 1) ? ETOT : row_start[n0 + 256];
    __syncthreads();
    for (int j = start + tid; j < end; j += 256) {
        unsigned p = bucket_buf[j];
        int d = (int)(p >> 16);
        int s = (int)(p & 0xffffu);
        int pos = atomicAdd(&cur[d - n0], 1);
        elist[pos] = s;
    }
}

// ============ fused gather GAT: chunked flash softmax + bf16 gather ============
__global__ __launch_bounds__(128) void gat_gather_kernel(const int* __restrict__ row_start,
                                                         const int* __restrict__ deg,
                                                         const int* __restrict__ elist,
                                                         const float* __restrict__ as,
                                                         const float* __restrict__ ad,
                                                         const unsigned short* __restrict__ H16,
                                                         const float* __restrict__ bias,
                                                         float* __restrict__ out) {
    const int n = blockIdx.x;
    const int t = threadIdx.x;
    const int c = t;            // channel (gather phase)
    const int hg = t >> 5;      // head
    const int j32 = t & 31;     // edge-in-chunk (softmax phase)
    const int row = row_start[n];
    const int len = deg[n];
    const float ad_n = ad[n * 4 + hg];

    __shared__ int   sbuf[32];
    __shared__ float pbuf[4][32];

    float m = -INFINITY, z = 0.f, acc = 0.f;

    for (int base = 0; base < len; base += 32) {
        const int cl = min(32, len - base);
        if (t < cl) sbuf[t] = elist[row + base + t];
        __syncthreads();

        float ev = -INFINITY;
        if (j32 < cl) {
            int s = sbuf[j32];
            ev = as[s * 4 + hg] + ad_n;
            ev = ev > 0.f ? ev : ev * NEG_SLOPE;
        }
        float cm = ev;
#pragma unroll
        for (int off = 16; off > 0; off >>= 1)
            cm = fmaxf(cm, __shfl_xor(cm, off, 32));
        float mnew = fmaxf(m, cm);
        float scale = __expf(m - mnew);
        z *= scale;
        acc *= scale;
        m = mnew;
        float p = (j32 < cl) ? __expf(ev - m) : 0.f;
        float ps = p;
#pragma unroll
        for (int off = 16; off > 0; off >>= 1)
            ps += __shfl_xor(ps, off, 32);
        z += ps;
        pbuf[hg][j32] = p;
        __syncthreads();

        for (int j = 0; j < cl; ++j) {
            int s = sbuf[j];
            unsigned short us = H16[(size_t)s * HC + c];
            float hv = __uint_as_float((unsigned)us << 16);
            acc = fmaf(pbuf[hg][j], hv, acc);
        }
        __syncthreads();
    }
    float v = acc / z + bias[c];
    out[(size_t)n * HC + c] = v > 0.f ? v : 0.f;
}

// ---- graph boundaries via binary search on sorted batch ----
__global__ void boundary_kernel(const int* __restrict__ batch,
                                int* __restrict__ gstart,
                                float* __restrict__ cntf) {
    int g = threadIdx.x;
    if (g <= NUM_GRAPHS) {
        int lo = 0, hi = N_NODES;
        while (lo < hi) {
            int mid = (lo + hi) >> 1;
            if (batch[mid] < g) lo = mid + 1; else hi = mid;
        }
        gstart[g] = lo;
    }
    __syncthreads();
    if (g < NUM_GRAPHS) cntf[g] = (float)(gstart[g + 1] - gstart[g]);
}

// ---- pool: 8 blocks per graph, register accumulation, 1 atomic per thread ----
__global__ __launch_bounds__(128) void pool_seg_kernel(const float* __restrict__ out,
                                                       const int* __restrict__ gstart,
                                                       float* __restrict__ sums) {
    const int g = blockIdx.x >> 3;
    const int split = blockIdx.x & 7;
    const int c = threadIdx.x;
    const int start = gstart[g], end = gstart[g + 1];
    const int len = end - start;
    const int chunk = (len + POOL_SPLIT - 1) / POOL_SPLIT;
    const int s0 = start + split * chunk;
    const int s1 = min(s0 + chunk, end);
    float acc = 0.f;
    for (int n = s0; n < s1; ++n) acc += out[(size_t)n * HC + c];
    if (s0 < s1) atomicAdd(&sums[g * HC + c], acc);
}

// ---- classifier ----
__global__ void classifier_kernel(const float* __restrict__ sums,
                                  const float* __restrict__ cnt,
                                  const float* __restrict__ Wc1,
                                  const float* __restrict__ bc1,
                                  const float* __restrict__ Wc2,
                                  const float* __restrict__ bc2,
                                  float* __restrict__ outp) {
    int g = threadIdx.x;
    if (g >= NUM_GRAPHS) return;
    float inv = 1.0f / cnt[g];
    float hidden[C_CH];
#pragma unroll 4
    for (int j = 0; j < C_CH; ++j) {
        float acc = bc1[j];
        for (int c = 0; c < HC; ++c)
            acc += (sums[g * HC + c] * inv) * Wc1[c * C_CH + j];
        hidden[j] = acc;
    }
    for (int k = 0; k < NUM_CLASSES; ++k) {
        float acc = bc2[k];
#pragma unroll
        for (int j = 0; j < C_CH; ++j) acc += hidden[j] * Wc2[j * NUM_CLASSES + k];
        outp[g * NUM_CLASSES + k] = 1.0f / (1.0f + __expf(-acc));
    }
}

extern "C" void kernel_launch(void* const* d_in, const int* in_sizes, int n_in,
                              void* d_out, int out_size, void* d_ws, size_t ws_size,
                              hipStream_t stream) {
    const float* x   = (const float*)d_in[0];
    const int*   ei  = (const int*)  d_in[1];
    const int*   bat = (const int*)  d_in[2];
    const float* W1  = (const float*)d_in[3];
    const float* as1 = (const float*)d_in[4];
    const float* ad1 = (const float*)d_in[5];
    const float* b1  = (const float*)d_in[6];
    const float* W2  = (const float*)d_in[7];
    const float* as2 = (const float*)d_in[8];
    const float* ad2 = (const float*)d_in[9];
    const float* b2  = (const float*)d_in[10];
    const float* Wc1 = (const float*)d_in[11];
    const float* bc1 = (const float*)d_in[12];
    const float* Wc2 = (const float*)d_in[13];
    const float* bc2 = (const float*)d_in[14];
    float* outp = (float*)d_out;

    char* ws = (char*)d_ws;
    float* hbuf = (float*)ws;  ws += (size_t)N_NODES * HC * 4;
    float* obuf = (float*)ws;  ws += (size_t)N_NODES * HC * 4;
    unsigned short* hb16 = (unsigned short*)ws; ws += (size_t)N_NODES * HC * 2;
    float* asb  = (float*)ws;  ws += (size_t)N_NODES * H_HEADS * 4;
    float* adb  = (float*)ws;  ws += (size_t)N_NODES * H_HEADS * 4;
    int* elist    = (int*)ws;  ws += (size_t)ETOT * 4;
    unsigned* bucket_buf = (unsigned*)ws; ws += (size_t)ETOT * 4;
    int* row_start= (int*)ws;  ws += (size_t)N_NODES * 4;
    int* degb     = (int*)ws;  ws += (size_t)N_NODES * 4;
    int* bcursor  = (int*)ws;  ws += (size_t)NBUCK * 4;
    int* bsum     = (int*)ws;  ws += 256 * 4;
    int* gstart   = (int*)ws;  ws += (NUM_GRAPHS + 1) * 4;
    float* sums = (float*)ws;  ws += (size_t)NUM_GRAPHS * HC * 4;
    float* cnt  = (float*)ws;  ws += (size_t)NUM_GRAPHS * 4;

    const int nh_blocks  = (N_NODES * H_HEADS + 255) / 256;
    const int n_blocks   = (N_NODES + 255) / 256;
    const int e_blocks   = (ETOT + 255) / 256;
    const int gemm_blocks = (N_NODES + 63) / 64;

    // ---------------- CSR build (shared by both layers) ----------------
    hipMemsetAsync(degb, 0, (size_t)N_NODES * 4, stream);
    count_deg_kernel<<<e_blocks, 256, 0, stream>>>(ei, degb);
    scan_block_kernel<<<SCAN_BLOCKS, 256, 0, stream>>>(degb, row_start, bsum);
    scan_tops_kernel<<<1, 256, 0, stream>>>(bsum);
    scan_add_kernel<<<n_blocks, 256, 0, stream>>>(row_start, bsum, bcursor);
    bucket_scatter_kernel<<<SCAT_BLOCKS, 256, 0, stream>>>(ei, bcursor, bucket_buf);
    bucket_sort_kernel<<<NBUCK, 256, 0, stream>>>(bucket_buf, row_start, elist);

    // ---------------- layer 1 ----------------
    gemm_rb<F_IN_DIM><<<gemm_blocks, 256, 0, stream>>>(x, W1, hbuf, hb16);
    alpha_kernel<<<nh_blocks, 256, 0, stream>>>(hbuf, as1, ad1, asb, adb);
    gat_gather_kernel<<<N_NODES, 128, 0, stream>>>(row_start, degb, elist,
                                                   asb, adb, hb16, b1, obuf);

    // ---------------- layer 2 ----------------
    gemm_rb<HC><<<gemm_blocks, 256, 0, stream>>>(obuf, W2, hbuf, hb16);
    alpha_kernel<<<nh_blocks, 256, 0, stream>>>(hbuf, as2, ad2, asb, adb);
    gat_gather_kernel<<<N_NODES, 128, 0, stream>>>(row_start, degb, elist,
                                                   asb, adb, hb16, b2, obuf);

    // ---------------- pool + classifier ----------------
    boundary_kernel<<<1, 128, 0, stream>>>(bat, gstart, cnt);
    hipMemsetAsync(sums, 0, (size_t)NUM_GRAPHS * HC * 4, stream);
    pool_seg_kernel<<<NUM_GRAPHS * POOL_SPLIT, 128, 0, stream>>>(obuf, gstart, sums);
    classifier_kernel<<<1, 64, 0, stream>>>(sums, cnt, Wc1, bc1, Wc2, bc2, outp);
}